// Round 6
// baseline (1455.977 us; speedup 1.0000x reference)
//
#include <hip/hip_runtime.h>
#include <hip/hip_bf16.h>

#define BB 8
#define CC 16
#define HH 128
#define WW 128
#define HD 64
#define WD 64
#define LP 4096
#define K1 144
#define KP 160
#define N2 256
#define NS 4
#define NCH 32   // (LP/NS)/32 chunks per block

typedef __attribute__((ext_vector_type(8))) short bf16x8;
typedef __attribute__((ext_vector_type(4))) float f32x4;

__device__ __forceinline__ unsigned short pack_rne(float x) {
    unsigned int u = __float_as_uint(x);
    return (unsigned short)((u + 0x7FFFu + ((u >> 16) & 1u)) >> 16);
}
__device__ __forceinline__ float bf2f(unsigned short u) {
    return __uint_as_float(((unsigned int)u) << 16);
}
__device__ __forceinline__ float ld_in(const void* p, long idx, int bf) {
    if (bf) return bf2f(((const unsigned short*)p)[idx]);
    return ((const float*)p)[idx];
}
__device__ __forceinline__ void gl_lds16(const void* g, void* l) {
    __builtin_amdgcn_global_load_lds(
        (const __attribute__((address_space(1))) unsigned int*)g,
        (__attribute__((address_space(3))) unsigned int*)l,
        16, 0, 0);
}

// ---------------------------------------------------------------------------
__global__ void detect_kernel(const unsigned int* __restrict__ w, int* __restrict__ flag) {
    if (threadIdx.x == 0) {
        int cnt = 0;
        for (int i = 0; i < 256; i++) {
            unsigned int e = (w[i] >> 7) & 0xFF;
            if (e >= 100 && e <= 140) cnt++;
        }
        *flag = (cnt >= 192) ? 1 : 0;
    }
}

// ---------------------------------------------------------------------------
// prep v2: one wave per patch; shuffle-butterfly reductions, no LDS/barriers.
// ---------------------------------------------------------------------------
__global__ __launch_bounds__(256) void prep_kernel(
    const void* __restrict__ fg, const void* __restrict__ bg,
    const void* __restrict__ mask, const int* __restrict__ flagp,
    unsigned short* __restrict__ Fh, unsigned short* __restrict__ Fl,
    unsigned short* __restrict__ Kh, unsigned short* __restrict__ Kl,
    float* __restrict__ mmg)
{
    int bf = *flagp;
    int wave = threadIdx.x >> 6, lane = threadIdx.x & 63;
    int bl = blockIdx.x * 4 + wave;
    int b = bl >> 12, l = bl & 4095;
    int py = l >> 6, px = l & 63;

    float fgv[3], bgv[3];
    float ss = 0.f;
#pragma unroll
    for (int j = 0; j < 3; j++) {
        int e = lane + 64 * j;
        fgv[j] = 0.f; bgv[j] = 0.f;
        if (e < K1) {
            int c = e / 9;
            int r9 = e - c * 9;
            int ky = r9 / 3, kx = r9 - ky * 3;
            int yy = py + ky - 1, xx = px + kx - 1;
            if (yy >= 0 && yy < HD && xx >= 0 && xx < WD) {
                long base = ((long)(b * CC + c) * HH + 2 * yy) * WW + 2 * xx;
                fgv[j] = ld_in(fg, base, bf);
                bgv[j] = ld_in(bg, base, bf);
            }
        }
        ss += bgv[j] * bgv[j];
    }
#pragma unroll
    for (int s = 1; s < 64; s <<= 1) ss += __shfl_xor(ss, s);
    float rn = 1.0f / fmaxf(sqrtf(ss), 1e-4f);

    float mv = 0.f;
    if (lane < 9) {
        int ky = lane / 3, kx = lane - ky * 3;
        int yy = py + ky - 1, xx = px + kx - 1;
        if (yy >= 0 && yy < HD && xx >= 0 && xx < WD)
            mv = ld_in(mask, ((long)b * HH + 2 * yy) * WW + 2 * xx, bf);
    }
#pragma unroll
    for (int s = 1; s < 16; s <<= 1) mv += __shfl_xor(mv, s);
    if (lane == 0) mmg[bl] = (mv == 0.0f) ? 1.0f : 0.0f;

    long base = (long)bl * KP;
#pragma unroll
    for (int j = 0; j < 3; j++) {
        int e = lane + 64 * j;
        if (e < KP) {
            float f = fgv[j];
            float kv = bgv[j] * rn;
            unsigned short fh = pack_rne(f);
            unsigned short fl = pack_rne(f - bf2f(fh));
            unsigned short kh = pack_rne(kv);
            unsigned short kl = pack_rne(kv - bf2f(kh));
            Fh[base + e] = fh; Fl[base + e] = fl;
            Kh[base + e] = kh; Kl[base + e] = kl;
        }
    }
}

// ---------------------------------------------------------------------------
__global__ __launch_bounds__(256) void vT_kernel(
    const void* __restrict__ bg, const int* __restrict__ flagp,
    unsigned short* __restrict__ VT)
{
    int bf = *flagp;
    int l0 = blockIdx.x * 16;
    int b = blockIdx.y;
    int j = threadIdx.x;
    int c = j >> 4, dy = (j >> 2) & 3, dx = j & 3;

    unsigned short buf[16];
#pragma unroll
    for (int i = 0; i < 16; i++) {
        int l = l0 + i;
        int ly = l >> 6, lx = l & 63;
        int Y = 2 * ly + dy - 1, X = 2 * lx + dx - 1;
        float v = 0.f;
        if (Y >= 0 && Y < HH && X >= 0 && X < WW)
            v = ld_in(bg, ((long)(b * CC + c) * HH + Y) * WW + X, bf);
        buf[i] = pack_rne(v);
    }
    uint4* dst = (uint4*)&VT[((size_t)(b * N2 + j)) * LP + l0];
    dst[0] = *(uint4*)&buf[0];
    dst[1] = *(uint4*)&buf[8];
}

// ---------------------------------------------------------------------------
// flash v4: r5 structure + T14 issue-early V.
// r5 PMC analysis: O-phase serialized {load 4 V frags -> vmcnt stall ~500cy
// -> 4 MFMA} x4 groups = ~2000cy exposed L2 latency per wave-chunk = the
// dominant cost (all pipes <15%). Fix: all 16 V-frag loads (+2 mm loads)
// issued at chunk TOP (depend only on l0), pinned with sched_barrier(0);
// consumed ~1500cy later in O phase. +64 VGPR; __launch_bounds__(256,3)
// keeps 3 waves/SIMD (LDS 46KB caps 3 blocks/CU anyway -> no occ loss).
// ---------------------------------------------------------------------------
__global__ __launch_bounds__(256, 3) void flash_kernel(
    const unsigned short* __restrict__ Fh, const unsigned short* __restrict__ Fl,
    const unsigned short* __restrict__ Kh, const unsigned short* __restrict__ Kl,
    const unsigned short* __restrict__ VT,  // [BB][256][4096]
    const float* __restrict__ mmg,          // [BB][4096]
    float* __restrict__ Up,                 // [NS][BB][4096][256]
    float* __restrict__ Dp)                 // [NS][BB][4096]
{
    __shared__ unsigned short KsS[2][2][32][160];   // [buf][h/l][row][k] 40 KB
    __shared__ unsigned short P_lds[4][16][40];     // per-wave P tile 5 KB

    int t = threadIdx.x;
    int wave = t >> 6, lane = t & 63;
    int l15 = lane & 15, lq = lane >> 4;

    int b  = blockIdx.z;
    int sp = blockIdx.y;
    int pw = blockIdx.x * 64 + wave * 16;
    int lbase = sp * (LP / NS);

    const unsigned short* Fh_b = Fh + (size_t)b * LP * KP;
    const unsigned short* Fl_b = Fl + (size_t)b * LP * KP;
    const unsigned short* Kh_b = Kh + (size_t)b * LP * KP;
    const unsigned short* Kl_b = Kl + (size_t)b * LP * KP;
    const unsigned short* VT_b = VT + (size_t)b * N2 * LP;
    const float* mm_b = mmg + (size_t)b * LP;

    // ---- staging precompute: this wave stages bytes [wave*5120, +5120) of
    // the 20 KB K-region (flat over [hl][row][o]); 5 calls of 1 KB.
    const unsigned short* ksrc[5];
    int krow_s[5];
#pragma unroll
    for (int i = 0; i < 5; i++) {
        int x = wave * 5120 + i * 1024 + lane * 16;  // flat byte
        int hl = (x >= 10240);
        int o2 = x - hl * 10240;
        int row = o2 / 320;
        int o = o2 - row * 320;
        int osw = o ^ ((row & 3) << 4);              // source swizzle
        ksrc[i] = (hl ? Kl_b : Kh_b) + (osw >> 1);
        krow_s[i] = row;
    }
    char* lds0 = (char*)KsS + wave * 5120;

    // ---- F fragments: rows pw..pw+15, k = kc*32 + lq*8
    bf16x8 fh[5], fl[5];
    {
        size_t fbase = (size_t)(pw + l15) * KP + lq * 8;
#pragma unroll
        for (int kc = 0; kc < 5; kc++) {
            fh[kc] = *(const bf16x8*)&Fh_b[fbase + kc * 32];
            fl[kc] = *(const bf16x8*)&Fl_b[fbase + kc * 32];
        }
    }

    f32x4 zero4 = {0.f, 0.f, 0.f, 0.f};
    f32x4 acc[16];
#pragma unroll
    for (int n = 0; n < 16; n++) acc[n] = zero4;
    float d_[4] = {0.f, 0.f, 0.f, 0.f};

    // prologue: stage chunk 0 into buf 0
    {
        size_t lrow = (size_t)lbase * KP;
#pragma unroll
        for (int i = 0; i < 5; i++)
            gl_lds16(ksrc[i] + lrow + (size_t)krow_s[i] * KP, lds0 + i * 1024);
    }

    for (int ch = 0; ch < NCH; ch++) {
        int cur = ch & 1;
        int l0 = lbase + ch * 32;
        __syncthreads();   // drains staging of buf[cur]; fences prev reads

        // ---- issue-early: all 16 V frags + mm for THIS chunk (dep only on l0)
        bf16x8 vb[16];
#pragma unroll
        for (int g = 0; g < 4; g++) {
            size_t vbase = (size_t)(g * 64 + l15) * LP + l0 + lq * 8;
#pragma unroll
            for (int nn = 0; nn < 4; nn++)
                vb[g * 4 + nn] = *(const bf16x8*)&VT_b[vbase + (size_t)(nn * 16) * LP];
        }
        float mmh[2];
        mmh[0] = mm_b[l0 + l15];
        mmh[1] = mm_b[l0 + 16 + l15];

        // ---- issue K-stage for ch+1 (after V: FIFO keeps V waits cheap)
        if (ch + 1 < NCH) {
            size_t lrow = (size_t)(l0 + 32) * KP;
#pragma unroll
            for (int i = 0; i < 5; i++)
                gl_lds16(ksrc[i] + lrow + (size_t)krow_s[i] * KP,
                         lds0 + (cur ^ 1) * 20480 + i * 1024);
        }
        __builtin_amdgcn_sched_barrier(0);   // pin the issue-early region

        // ---- S phase: two 16-wide l-subtiles from LDS K
        float e_[2][4];
        int swb = (l15 & 3) << 4;
#pragma unroll
        for (int h = 0; h < 2; h++) {
            const char* kbase = (const char*)KsS + cur * 20480 + (h * 16 + l15) * 320;
            f32x4 s0 = zero4, s1 = zero4, s2 = zero4;
#pragma unroll
            for (int kc = 0; kc < 5; kc++) {
                int off = (kc * 64 + lq * 16) ^ swb;
                bf16x8 kvh = *(const bf16x8*)(kbase + off);
                s0 = __builtin_amdgcn_mfma_f32_16x16x32_bf16(fh[kc], kvh, s0, 0, 0, 0);
                s2 = __builtin_amdgcn_mfma_f32_16x16x32_bf16(fl[kc], kvh, s2, 0, 0, 0);
            }
#pragma unroll
            for (int kc = 0; kc < 5; kc++) {
                int off = (kc * 64 + lq * 16) ^ swb;
                bf16x8 kvl = *(const bf16x8*)(kbase + 10240 + off);
                s1 = __builtin_amdgcn_mfma_f32_16x16x32_bf16(fh[kc], kvl, s1, 0, 0, 0);
            }
            f32x4 s = (s0 + s1) + s2;
#pragma unroll
            for (int r = 0; r < 4; r++) {
                float z = (mmh[h] > 0.f) ? 10.f * s[r] : 0.f;
                float e = __expf(z - 60.f);
                d_[r] += e;
                e_[h][r] = e * mmh[h];
            }
        }

        // ---- P tile: D-frag -> [p][l] per-wave LDS, read back as A-frag
#pragma unroll
        for (int h = 0; h < 2; h++)
#pragma unroll
            for (int r = 0; r < 4; r++)
                P_lds[wave][lq * 4 + r][h * 16 + l15] = pack_rne(e_[h][r]);
        bf16x8 pa = *(const bf16x8*)&P_lds[wave][l15][lq * 8];

        // ---- O phase: 16 c-tiles, V already in registers
#pragma unroll
        for (int g = 0; g < 4; g++)
#pragma unroll
            for (int nn = 0; nn < 4; nn++)
                acc[g * 4 + nn] = __builtin_amdgcn_mfma_f32_16x16x32_bf16(pa, vb[g * 4 + nn], acc[g * 4 + nn], 0, 0, 0);
    }

    // ---- epilogue: finish partial denom across the 16 lanes of each row
#pragma unroll
    for (int s = 1; s < 16; s <<= 1)
#pragma unroll
        for (int r = 0; r < 4; r++) d_[r] += __shfl_xor(d_[r], s);

    if (l15 == 0) {
        float* dp = Dp + ((size_t)sp * BB + b) * LP;
#pragma unroll
        for (int r = 0; r < 4; r++) dp[pw + lq * 4 + r] = d_[r];
    }
    float* Uo = Up + ((size_t)sp * BB + b) * LP * N2;
#pragma unroll
    for (int g = 0; g < 4; g++)
#pragma unroll
        for (int nn = 0; nn < 4; nn++) {
            int col = g * 64 + nn * 16 + l15;
#pragma unroll
            for (int r = 0; r < 4; r++)
                Uo[(size_t)(pw + lq * 4 + r) * N2 + col] = acc[g * 4 + nn][r];
        }
}

// ---------------------------------------------------------------------------
// merge: U = (sum_sp Up) / (sum_sp Dp). Streaming, one row per block.
// ---------------------------------------------------------------------------
__global__ __launch_bounds__(256) void merge_kernel(
    const float* __restrict__ Up, const float* __restrict__ Dp,
    float* __restrict__ U)
{
    size_t row = blockIdx.x;            // b*LP + p
    int c = threadIdx.x;
    float d = 0.f, a = 0.f;
#pragma unroll
    for (int s = 0; s < NS; s++) {
        d += Dp[(size_t)s * BB * LP + row];
        a += Up[((size_t)s * BB * LP + row) * N2 + c];
    }
    U[row * N2 + c] = a / d;
}

// ---------------------------------------------------------------------------
// gather / overlap-add (upright), fp32 out
// ---------------------------------------------------------------------------
__global__ __launch_bounds__(256) void gather_kernel(
    const float* __restrict__ U, float* __restrict__ out)
{
    int idx = blockIdx.x * 256 + threadIdx.x;
    int ox = idx & 127;
    int t1 = idx >> 7;
    int oy = t1 & 127;
    int t2 = t1 >> 7;
    int c = t2 & 15;
    int b = t2 >> 4;

    float sum = 0.f;
    int d0y = (oy + 1) & 1, d0x = (ox + 1) & 1;
#pragma unroll
    for (int iy = 0; iy < 2; iy++) {
        int dy = d0y + 2 * iy;
        int y = (oy + 1 - dy) >> 1;
        if (y < 0 || y > 63) continue;
#pragma unroll
        for (int ix = 0; ix < 2; ix++) {
            int dx = d0x + 2 * ix;
            int x = (ox + 1 - dx) >> 1;
            if (x < 0 || x > 63) continue;
            sum += U[((long)b * LP + y * 64 + x) * N2 + c * 16 + dy * 4 + dx];
        }
    }
    out[idx] = sum * 0.25f;
}

// ---------------------------------------------------------------------------
extern "C" void kernel_launch(void* const* d_in, const int* in_sizes, int n_in,
                              void* d_out, int out_size, void* d_ws, size_t ws_size,
                              hipStream_t stream)
{
    const void* fg   = d_in[0];
    const void* bg   = d_in[1];
    const void* mask = d_in[2];
    float* out = (float*)d_out;

    char* w = (char*)d_ws;
    size_t o = 0;
    int*            flag = (int*)(w + o);            o += 16;
    unsigned short* Fh   = (unsigned short*)(w + o); o += (size_t)BB * LP * KP * 2;
    unsigned short* Fl   = (unsigned short*)(w + o); o += (size_t)BB * LP * KP * 2;
    unsigned short* Kh   = (unsigned short*)(w + o); o += (size_t)BB * LP * KP * 2;
    unsigned short* Kl   = (unsigned short*)(w + o); o += (size_t)BB * LP * KP * 2;
    unsigned short* VT   = (unsigned short*)(w + o); o += (size_t)BB * N2 * LP * 2;
    float*          U    = (float*)(w + o);          o += (size_t)BB * LP * N2 * 4;
    float*          mmg  = (float*)(w + o);          o += (size_t)BB * LP * 4;
    float*          Dp   = (float*)(w + o);          o += (size_t)NS * BB * LP * 4;
    float*          Up   = (float*)(w + o);          o += (size_t)NS * BB * LP * N2 * 4;

    detect_kernel<<<1, 64, 0, stream>>>((const unsigned int*)fg, flag);
    prep_kernel<<<BB * LP / 4, 256, 0, stream>>>(fg, bg, mask, flag, Fh, Fl, Kh, Kl, mmg);
    vT_kernel<<<dim3(LP / 16, BB), 256, 0, stream>>>(bg, flag, VT);

    flash_kernel<<<dim3(64, NS, BB), 256, 0, stream>>>(Fh, Fl, Kh, Kl, VT, mmg, Up, Dp);
    merge_kernel<<<BB * LP, 256, 0, stream>>>(Up, Dp, U);

    gather_kernel<<<(BB * CC * HH * WW) / 256, 256, 0, stream>>>(U, out);
}

// Round 8
// 504.672 us; speedup vs baseline: 2.8850x; 2.8850x over previous
//
#include <hip/hip_runtime.h>
#include <hip/hip_bf16.h>

#define BB 8
#define CC 16
#define HH 128
#define WW 128
#define HD 64
#define WD 64
#define LP 4096
#define K1 144
#define KP 160
#define N2 256
#define NS 4
#define NCH 32   // (LP/NS)/32 chunks per block

typedef __attribute__((ext_vector_type(8))) short bf16x8;
typedef __attribute__((ext_vector_type(4))) float f32x4;

__device__ __forceinline__ unsigned short pack_rne(float x) {
    unsigned int u = __float_as_uint(x);
    return (unsigned short)((u + 0x7FFFu + ((u >> 16) & 1u)) >> 16);
}
__device__ __forceinline__ float bf2f(unsigned short u) {
    return __uint_as_float(((unsigned int)u) << 16);
}
__device__ __forceinline__ float ld_in(const void* p, long idx, int bf) {
    if (bf) return bf2f(((const unsigned short*)p)[idx]);
    return ((const float*)p)[idx];
}
__device__ __forceinline__ void gl_lds16(const void* g, void* l) {
    __builtin_amdgcn_global_load_lds(
        (const __attribute__((address_space(1))) unsigned int*)g,
        (__attribute__((address_space(3))) unsigned int*)l,
        16, 0, 0);
}

// ---------------------------------------------------------------------------
__global__ void detect_kernel(const unsigned int* __restrict__ w, int* __restrict__ flag) {
    if (threadIdx.x == 0) {
        int cnt = 0;
        for (int i = 0; i < 256; i++) {
            unsigned int e = (w[i] >> 7) & 0xFF;
            if (e >= 100 && e <= 140) cnt++;
        }
        *flag = (cnt >= 192) ? 1 : 0;
    }
}

// ---------------------------------------------------------------------------
// prep v2: one wave per patch; shuffle-butterfly reductions, no LDS/barriers.
// ---------------------------------------------------------------------------
__global__ __launch_bounds__(256) void prep_kernel(
    const void* __restrict__ fg, const void* __restrict__ bg,
    const void* __restrict__ mask, const int* __restrict__ flagp,
    unsigned short* __restrict__ Fh, unsigned short* __restrict__ Fl,
    unsigned short* __restrict__ Kh, unsigned short* __restrict__ Kl,
    float* __restrict__ mmg)
{
    int bf = *flagp;
    int wave = threadIdx.x >> 6, lane = threadIdx.x & 63;
    int bl = blockIdx.x * 4 + wave;
    int b = bl >> 12, l = bl & 4095;
    int py = l >> 6, px = l & 63;

    float fgv[3], bgv[3];
    float ss = 0.f;
#pragma unroll
    for (int j = 0; j < 3; j++) {
        int e = lane + 64 * j;
        fgv[j] = 0.f; bgv[j] = 0.f;
        if (e < K1) {
            int c = e / 9;
            int r9 = e - c * 9;
            int ky = r9 / 3, kx = r9 - ky * 3;
            int yy = py + ky - 1, xx = px + kx - 1;
            if (yy >= 0 && yy < HD && xx >= 0 && xx < WD) {
                long base = ((long)(b * CC + c) * HH + 2 * yy) * WW + 2 * xx;
                fgv[j] = ld_in(fg, base, bf);
                bgv[j] = ld_in(bg, base, bf);
            }
        }
        ss += bgv[j] * bgv[j];
    }
#pragma unroll
    for (int s = 1; s < 64; s <<= 1) ss += __shfl_xor(ss, s);
    float rn = 1.0f / fmaxf(sqrtf(ss), 1e-4f);

    float mv = 0.f;
    if (lane < 9) {
        int ky = lane / 3, kx = lane - ky * 3;
        int yy = py + ky - 1, xx = px + kx - 1;
        if (yy >= 0 && yy < HD && xx >= 0 && xx < WD)
            mv = ld_in(mask, ((long)b * HH + 2 * yy) * WW + 2 * xx, bf);
    }
#pragma unroll
    for (int s = 1; s < 16; s <<= 1) mv += __shfl_xor(mv, s);
    if (lane == 0) mmg[bl] = (mv == 0.0f) ? 1.0f : 0.0f;

    long base = (long)bl * KP;
#pragma unroll
    for (int j = 0; j < 3; j++) {
        int e = lane + 64 * j;
        if (e < KP) {
            float f = fgv[j];
            float kv = bgv[j] * rn;
            unsigned short fh = pack_rne(f);
            unsigned short fl = pack_rne(f - bf2f(fh));
            unsigned short kh = pack_rne(kv);
            unsigned short kl = pack_rne(kv - bf2f(kh));
            Fh[base + e] = fh; Fl[base + e] = fl;
            Kh[base + e] = kh; Kl[base + e] = kl;
        }
    }
}

// ---------------------------------------------------------------------------
__global__ __launch_bounds__(256) void vT_kernel(
    const void* __restrict__ bg, const int* __restrict__ flagp,
    unsigned short* __restrict__ VT)
{
    int bf = *flagp;
    int l0 = blockIdx.x * 16;
    int b = blockIdx.y;
    int j = threadIdx.x;
    int c = j >> 4, dy = (j >> 2) & 3, dx = j & 3;

    unsigned short buf[16];
#pragma unroll
    for (int i = 0; i < 16; i++) {
        int l = l0 + i;
        int ly = l >> 6, lx = l & 63;
        int Y = 2 * ly + dy - 1, X = 2 * lx + dx - 1;
        float v = 0.f;
        if (Y >= 0 && Y < HH && X >= 0 && X < WW)
            v = ld_in(bg, ((long)(b * CC + c) * HH + Y) * WW + X, bf);
        buf[i] = pack_rne(v);
    }
    uint4* dst = (uint4*)&VT[((size_t)(b * N2 + j)) * LP + l0];
    dst[0] = *(uint4*)&buf[0];
    dst[1] = *(uint4*)&buf[8];
}

// ---------------------------------------------------------------------------
// flash v6: r7 structure with the swizzle REMOVED and conflict-free subtiled
// LDS layouts (s21-style [slot][row][16B]) instead.
// r7's NaN: (row&7)<<4 XOR spans 112B > the 64B row -> staging read wrong
// k-elements AND reads ran past KsS into VsS. Fix: no XOR at all; layouts
//   K: [hl][kc][slot(4)][row(32)][16B]   (20 KB per buffer)
//   V: [slot(4)][c(256)][16B]            (16 KB per buffer)
// A ds_read_b128 (lane: row=l15, slot=lq) then has consecutive-lane bank
// stride of 4 dwords -> lanes 0-7 cover all 32 banks once = conflict-free.
// Rest identical to r7: K+V double-buffered via global_load_lds, issued one
// chunk ahead, ONE barrier per chunk; fixed-shift-60 softmax; split-l NS=4
// with additive partials + merge. LDS 77 KB -> 2 blocks/CU.
// ---------------------------------------------------------------------------
__global__ __launch_bounds__(256) void flash_kernel(
    const unsigned short* __restrict__ Fh, const unsigned short* __restrict__ Fl,
    const unsigned short* __restrict__ Kh, const unsigned short* __restrict__ Kl,
    const unsigned short* __restrict__ VT,  // [BB][256][4096]
    const float* __restrict__ mmg,          // [BB][4096]
    float* __restrict__ Up,                 // [NS][BB][4096][256]
    float* __restrict__ Dp)                 // [NS][BB][4096]
{
    __shared__ char KsS[2][20480];                  // [hl][kc][slot][row][16B]
    __shared__ char VsS[2][16384];                  // [slot][c][16B]
    __shared__ unsigned short P_lds[4][16][40];     // per-wave P tile 5 KB

    int t = threadIdx.x;
    int wave = t >> 6, lane = t & 63;
    int l15 = lane & 15, lq = lane >> 4;

    int b  = blockIdx.z;
    int sp = blockIdx.y;
    int pw = blockIdx.x * 64 + wave * 16;
    int lbase = sp * (LP / NS);

    const unsigned short* Fh_b = Fh + (size_t)b * LP * KP;
    const unsigned short* Fl_b = Fl + (size_t)b * LP * KP;
    const unsigned short* Kh_b = Kh + (size_t)b * LP * KP;
    const unsigned short* Kl_b = Kl + (size_t)b * LP * KP;
    const unsigned short* VT_b = VT + (size_t)b * N2 * LP;
    const float* mm_b = mmg + (size_t)b * LP;

    // ---- K staging map: dest flat d over [hl][kc][slot][row][16B]
    const unsigned short* ksrc[5];
    int krow[5];
#pragma unroll
    for (int i = 0; i < 5; i++) {
        int d = wave * 5120 + i * 1024 + lane * 16;
        int hl = d / 10240;
        int r1 = d - hl * 10240;
        int kc = r1 >> 11;              // 2048 B per kc
        int r2 = r1 & 2047;
        int slot = r2 >> 9;             // 512 B per slot
        int row = (r2 & 511) >> 4;      // 16 B per row
        ksrc[i] = (hl ? Kl_b : Kh_b) + kc * 32 + slot * 8;
        krow[i] = row;
    }
    // ---- V staging map: dest flat d over [slot][c][16B]
    const unsigned short* vsrc[4];
#pragma unroll
    for (int i = 0; i < 4; i++) {
        int d = wave * 4096 + i * 1024 + lane * 16;
        int slot = d >> 12;             // 4096 B per slot
        int c = (d & 4095) >> 4;        // 16 B per c
        vsrc[i] = VT_b + (size_t)c * LP + slot * 8;
    }

    // ---- F fragments: rows pw..pw+15, k = kc*32 + lq*8
    bf16x8 fh[5], fl[5];
    {
        size_t fbase = (size_t)(pw + l15) * KP + lq * 8;
#pragma unroll
        for (int kc = 0; kc < 5; kc++) {
            fh[kc] = *(const bf16x8*)&Fh_b[fbase + kc * 32];
            fl[kc] = *(const bf16x8*)&Fl_b[fbase + kc * 32];
        }
    }

    f32x4 zero4 = {0.f, 0.f, 0.f, 0.f};
    f32x4 acc[16];
#pragma unroll
    for (int n = 0; n < 16; n++) acc[n] = zero4;
    float d_[4] = {0.f, 0.f, 0.f, 0.f};

    // ---- prologue: stage chunk 0 into buf 0
#pragma unroll
    for (int i = 0; i < 5; i++)
        gl_lds16(ksrc[i] + (size_t)(lbase + krow[i]) * KP, &KsS[0][wave * 5120 + i * 1024]);
#pragma unroll
    for (int i = 0; i < 4; i++)
        gl_lds16(vsrc[i] + lbase, &VsS[0][wave * 4096 + i * 1024]);

    for (int ch = 0; ch < NCH; ch++) {
        int cur = ch & 1;
        int l0 = lbase + ch * 32;
        __syncthreads();   // drains staging of buf[cur] (vmcnt0) + fences reads

        float mmh0 = mm_b[l0 + l15];
        float mmh1 = mm_b[l0 + 16 + l15];

        if (ch + 1 < NCH) {
            size_t ln = (size_t)(l0 + 32);
#pragma unroll
            for (int i = 0; i < 5; i++)
                gl_lds16(ksrc[i] + (ln + krow[i]) * KP, &KsS[cur ^ 1][wave * 5120 + i * 1024]);
#pragma unroll
            for (int i = 0; i < 4; i++)
                gl_lds16(vsrc[i] + ln, &VsS[cur ^ 1][wave * 4096 + i * 1024]);
        }

        // ---- S phase: two 16-wide l-subtiles from LDS K (3 indep chains)
        float e_[2][4];
#pragma unroll
        for (int h = 0; h < 2; h++) {
            // lane reads: slot=lq, row=h*16+l15 -> byte lq*512 + row*16
            const char* kb = &KsS[cur][lq * 512 + (h * 16 + l15) * 16];
            f32x4 s0 = zero4, s1 = zero4, s2 = zero4;
#pragma unroll
            for (int kc = 0; kc < 5; kc++) {
                bf16x8 kvh = *(const bf16x8*)(kb + kc * 2048);
                s0 = __builtin_amdgcn_mfma_f32_16x16x32_bf16(fh[kc], kvh, s0, 0, 0, 0);
                s2 = __builtin_amdgcn_mfma_f32_16x16x32_bf16(fl[kc], kvh, s2, 0, 0, 0);
            }
#pragma unroll
            for (int kc = 0; kc < 5; kc++) {
                bf16x8 kvl = *(const bf16x8*)(kb + 10240 + kc * 2048);
                s1 = __builtin_amdgcn_mfma_f32_16x16x32_bf16(fh[kc], kvl, s1, 0, 0, 0);
            }
            f32x4 s = (s0 + s1) + s2;
            float mmh = (h == 0) ? mmh0 : mmh1;
#pragma unroll
            for (int r = 0; r < 4; r++) {
                float z = (mmh > 0.f) ? 10.f * s[r] : 0.f;
                float e = __expf(z - 60.f);
                d_[r] += e;
                e_[h][r] = e * mmh;
            }
        }

        // ---- P tile: D-frag -> [p][l] per-wave LDS, read back as A-frag
#pragma unroll
        for (int h = 0; h < 2; h++)
#pragma unroll
            for (int r = 0; r < 4; r++)
                P_lds[wave][lq * 4 + r][h * 16 + l15] = pack_rne(e_[h][r]);
        bf16x8 pa = *(const bf16x8*)&P_lds[wave][l15][lq * 8];

        // ---- O phase: 16 c-tiles from LDS V (slot=lq, row=c)
        const char* vbb = &VsS[cur][lq * 4096];
#pragma unroll
        for (int g = 0; g < 4; g++) {
            bf16x8 vb[4];
#pragma unroll
            for (int nn = 0; nn < 4; nn++)
                vb[nn] = *(const bf16x8*)(vbb + (g * 64 + nn * 16 + l15) * 16);
#pragma unroll
            for (int nn = 0; nn < 4; nn++)
                acc[g * 4 + nn] = __builtin_amdgcn_mfma_f32_16x16x32_bf16(pa, vb[nn], acc[g * 4 + nn], 0, 0, 0);
        }
    }

    // ---- epilogue: finish partial denom across the 16 lanes of each row
#pragma unroll
    for (int s = 1; s < 16; s <<= 1)
#pragma unroll
        for (int r = 0; r < 4; r++) d_[r] += __shfl_xor(d_[r], s);

    if (l15 == 0) {
        float* dp = Dp + ((size_t)sp * BB + b) * LP;
#pragma unroll
        for (int r = 0; r < 4; r++) dp[pw + lq * 4 + r] = d_[r];
    }
    float* Uo = Up + ((size_t)sp * BB + b) * LP * N2;
#pragma unroll
    for (int g = 0; g < 4; g++)
#pragma unroll
        for (int nn = 0; nn < 4; nn++) {
            int col = g * 64 + nn * 16 + l15;
#pragma unroll
            for (int r = 0; r < 4; r++)
                Uo[(size_t)(pw + lq * 4 + r) * N2 + col] = acc[g * 4 + nn][r];
        }
}

// ---------------------------------------------------------------------------
// merge: U = (sum_sp Up) / (sum_sp Dp). Streaming, one row per block.
// ---------------------------------------------------------------------------
__global__ __launch_bounds__(256) void merge_kernel(
    const float* __restrict__ Up, const float* __restrict__ Dp,
    float* __restrict__ U)
{
    size_t row = blockIdx.x;            // b*LP + p
    int c = threadIdx.x;
    float d = 0.f, a = 0.f;
#pragma unroll
    for (int s = 0; s < NS; s++) {
        d += Dp[(size_t)s * BB * LP + row];
        a += Up[((size_t)s * BB * LP + row) * N2 + c];
    }
    U[row * N2 + c] = a / d;
}

// ---------------------------------------------------------------------------
// gather / overlap-add (upright), fp32 out
// ---------------------------------------------------------------------------
__global__ __launch_bounds__(256) void gather_kernel(
    const float* __restrict__ U, float* __restrict__ out)
{
    int idx = blockIdx.x * 256 + threadIdx.x;
    int ox = idx & 127;
    int t1 = idx >> 7;
    int oy = t1 & 127;
    int t2 = t1 >> 7;
    int c = t2 & 15;
    int b = t2 >> 4;

    float sum = 0.f;
    int d0y = (oy + 1) & 1, d0x = (ox + 1) & 1;
#pragma unroll
    for (int iy = 0; iy < 2; iy++) {
        int dy = d0y + 2 * iy;
        int y = (oy + 1 - dy) >> 1;
        if (y < 0 || y > 63) continue;
#pragma unroll
        for (int ix = 0; ix < 2; ix++) {
            int dx = d0x + 2 * ix;
            int x = (ox + 1 - dx) >> 1;
            if (x < 0 || x > 63) continue;
            sum += U[((long)b * LP + y * 64 + x) * N2 + c * 16 + dy * 4 + dx];
        }
    }
    out[idx] = sum * 0.25f;
}

// ---------------------------------------------------------------------------
extern "C" void kernel_launch(void* const* d_in, const int* in_sizes, int n_in,
                              void* d_out, int out_size, void* d_ws, size_t ws_size,
                              hipStream_t stream)
{
    const void* fg   = d_in[0];
    const void* bg   = d_in[1];
    const void* mask = d_in[2];
    float* out = (float*)d_out;

    char* w = (char*)d_ws;
    size_t o = 0;
    int*            flag = (int*)(w + o);            o += 16;
    unsigned short* Fh   = (unsigned short*)(w + o); o += (size_t)BB * LP * KP * 2;
    unsigned short* Fl   = (unsigned short*)(w + o); o += (size_t)BB * LP * KP * 2;
    unsigned short* Kh   = (unsigned short*)(w + o); o += (size_t)BB * LP * KP * 2;
    unsigned short* Kl   = (unsigned short*)(w + o); o += (size_t)BB * LP * KP * 2;
    unsigned short* VT   = (unsigned short*)(w + o); o += (size_t)BB * N2 * LP * 2;
    float*          U    = (float*)(w + o);          o += (size_t)BB * LP * N2 * 4;
    float*          mmg  = (float*)(w + o);          o += (size_t)BB * LP * 4;
    float*          Dp   = (float*)(w + o);          o += (size_t)NS * BB * LP * 4;
    float*          Up   = (float*)(w + o);          o += (size_t)NS * BB * LP * N2 * 4;

    detect_kernel<<<1, 64, 0, stream>>>((const unsigned int*)fg, flag);
    prep_kernel<<<BB * LP / 4, 256, 0, stream>>>(fg, bg, mask, flag, Fh, Fl, Kh, Kl, mmg);
    vT_kernel<<<dim3(LP / 16, BB), 256, 0, stream>>>(bg, flag, VT);

    flash_kernel<<<dim3(64, NS, BB), 256, 0, stream>>>(Fh, Fl, Kh, Kl, VT, mmg, Up, Dp);
    merge_kernel<<<BB * LP, 256, 0, stream>>>(Up, Dp, U);

    gather_kernel<<<(BB * CC * HH * WW) / 256, 256, 0, stream>>>(U, out);
}

// Round 9
// 311.674 us; speedup vs baseline: 4.6715x; 1.6192x over previous
//
#include <hip/hip_runtime.h>
#include <hip/hip_bf16.h>
#include <hip/hip_fp16.h>

#define BB 8
#define CC 16
#define HH 128
#define WW 128
#define HD 64
#define WD 64
#define LP 4096
#define K1 144
#define KP 160
#define N2 256
#define NS 2
#define NCH 64   // (LP/NS)/32 chunks per block

typedef __attribute__((ext_vector_type(8))) short bf16x8;
typedef __attribute__((ext_vector_type(8))) _Float16 f16x8;
typedef __attribute__((ext_vector_type(4))) float f32x4;

__device__ __forceinline__ unsigned short pack_rne(float x) {
    unsigned int u = __float_as_uint(x);
    return (unsigned short)((u + 0x7FFFu + ((u >> 16) & 1u)) >> 16);
}
__device__ __forceinline__ float bf2f(unsigned short u) {
    return __uint_as_float(((unsigned int)u) << 16);
}
__device__ __forceinline__ unsigned short f2h(float x) {
    return __half_as_ushort(__float2half(x));   // RNE
}
__device__ __forceinline__ float ld_in(const void* p, long idx, int bf) {
    if (bf) return bf2f(((const unsigned short*)p)[idx]);
    return ((const float*)p)[idx];
}
__device__ __forceinline__ void gl_lds16(const void* g, void* l) {
    __builtin_amdgcn_global_load_lds(
        (const __attribute__((address_space(1))) unsigned int*)g,
        (__attribute__((address_space(3))) unsigned int*)l,
        16, 0, 0);
}

// ---------------------------------------------------------------------------
__global__ void detect_kernel(const unsigned int* __restrict__ w, int* __restrict__ flag) {
    if (threadIdx.x == 0) {
        int cnt = 0;
        for (int i = 0; i < 256; i++) {
            unsigned int e = (w[i] >> 7) & 0xFF;
            if (e >= 100 && e <= 140) cnt++;
        }
        *flag = (cnt >= 192) ? 1 : 0;
    }
}

// ---------------------------------------------------------------------------
// prep v3: one wave per patch; shuffle-butterfly reductions. Outputs are now
// single-pass f16 (Fp, Kp) -- S-phase precision analysis: F ~ N(0,1), K
// unit-normalized, f16 (2^-11) gives z error ~5e-3, well within threshold.
// ---------------------------------------------------------------------------
__global__ __launch_bounds__(256) void prep_kernel(
    const void* __restrict__ fg, const void* __restrict__ bg,
    const void* __restrict__ mask, const int* __restrict__ flagp,
    unsigned short* __restrict__ Fp, unsigned short* __restrict__ Kp,
    float* __restrict__ mmg)
{
    int bf = *flagp;
    int wave = threadIdx.x >> 6, lane = threadIdx.x & 63;
    int bl = blockIdx.x * 4 + wave;
    int b = bl >> 12, l = bl & 4095;
    int py = l >> 6, px = l & 63;

    float fgv[3], bgv[3];
    float ss = 0.f;
#pragma unroll
    for (int j = 0; j < 3; j++) {
        int e = lane + 64 * j;
        fgv[j] = 0.f; bgv[j] = 0.f;
        if (e < K1) {
            int c = e / 9;
            int r9 = e - c * 9;
            int ky = r9 / 3, kx = r9 - ky * 3;
            int yy = py + ky - 1, xx = px + kx - 1;
            if (yy >= 0 && yy < HD && xx >= 0 && xx < WD) {
                long base = ((long)(b * CC + c) * HH + 2 * yy) * WW + 2 * xx;
                fgv[j] = ld_in(fg, base, bf);
                bgv[j] = ld_in(bg, base, bf);
            }
        }
        ss += bgv[j] * bgv[j];
    }
#pragma unroll
    for (int s = 1; s < 64; s <<= 1) ss += __shfl_xor(ss, s);
    float rn = 1.0f / fmaxf(sqrtf(ss), 1e-4f);

    float mv = 0.f;
    if (lane < 9) {
        int ky = lane / 3, kx = lane - ky * 3;
        int yy = py + ky - 1, xx = px + kx - 1;
        if (yy >= 0 && yy < HD && xx >= 0 && xx < WD)
            mv = ld_in(mask, ((long)b * HH + 2 * yy) * WW + 2 * xx, bf);
    }
#pragma unroll
    for (int s = 1; s < 16; s <<= 1) mv += __shfl_xor(mv, s);
    if (lane == 0) mmg[bl] = (mv == 0.0f) ? 1.0f : 0.0f;

    long base = (long)bl * KP;
#pragma unroll
    for (int j = 0; j < 3; j++) {
        int e = lane + 64 * j;
        if (e < KP) {
            Fp[base + e] = f2h(fgv[j]);          // 0 beyond K1 -> zero pad
            Kp[base + e] = f2h(bgv[j] * rn);
        }
    }
}

// ---------------------------------------------------------------------------
__global__ __launch_bounds__(256) void vT_kernel(
    const void* __restrict__ bg, const int* __restrict__ flagp,
    unsigned short* __restrict__ VT)
{
    int bf = *flagp;
    int l0 = blockIdx.x * 16;
    int b = blockIdx.y;
    int j = threadIdx.x;
    int c = j >> 4, dy = (j >> 2) & 3, dx = j & 3;

    unsigned short buf[16];
#pragma unroll
    for (int i = 0; i < 16; i++) {
        int l = l0 + i;
        int ly = l >> 6, lx = l & 63;
        int Y = 2 * ly + dy - 1, X = 2 * lx + dx - 1;
        float v = 0.f;
        if (Y >= 0 && Y < HH && X >= 0 && X < WW)
            v = ld_in(bg, ((long)(b * CC + c) * HH + Y) * WW + X, bf);
        buf[i] = pack_rne(v);
    }
    uint4* dst = (uint4*)&VT[((size_t)(b * N2 + j)) * LP + l0];
    dst[0] = *(uint4*)&buf[0];
    dst[1] = *(uint4*)&buf[8];
}

// ---------------------------------------------------------------------------
// flash v7: (a) S-phase single-pass f16 (10 K-reads+30 MFMA -> 5+10 per
// 16-row half); (b) 32 p-rows per wave -- K/V frags in regs reused across
// both row-halves, halving LDS-read pressure per output (r8 PMC: LDS ~51%
// busy, the top consumer); (c) NS=2, grid (32,2,8)=512 = exactly 2
// blocks/CU, halves Up/merge traffic.
// Per wave-chunk: 10 K + 16 V + 2 P ds_read_b128, 20 f16 + 32 bf16 MFMA,
// for 32 rows x 256 cols. LDS: concat [K 10KB | V 16KB] x2 dbuf + P 10KB
// = 62 KB. P/V stay bf16 (P ~ e^-25 underflows f16 subnormals).
// Spill tell: FETCH >> 300 MB => acc/F spilled.
// ---------------------------------------------------------------------------
__global__ __launch_bounds__(256, 2) void flash_kernel(
    const unsigned short* __restrict__ Fp, const unsigned short* __restrict__ Kp,
    const unsigned short* __restrict__ VT,  // [BB][256][4096] bf16
    const float* __restrict__ mmg,          // [BB][4096]
    float* __restrict__ Up,                 // [NS][BB][4096][256]
    float* __restrict__ Dp)                 // [NS][BB][4096]
{
    __shared__ char S_lds[2][26624];                // [K 10240 | V 16384]
    __shared__ unsigned short P_lds[4][2][16][40];  // per-wave, per-row-half

    int t = threadIdx.x;
    int wave = t >> 6, lane = t & 63;
    int l15 = lane & 15, lq = lane >> 4;

    int b = blockIdx.z, sp = blockIdx.y;
    int pw = blockIdx.x * 128 + wave * 32;
    int lbase = sp * (LP / NS);

    const unsigned short* Fp_b = Fp + (size_t)b * LP * KP;
    const unsigned short* Kp_b = Kp + (size_t)b * LP * KP;
    const unsigned short* VT_b = VT + (size_t)b * N2 * LP;
    const float* mm_b = mmg + (size_t)b * LP;

    // staging: 26 x 1KB calls, call i handled by wave i%4 (j = i/4).
    // i<10 -> K region [kc(5)][slot(4)][row(32)][16B]; else V [slot(4)][c(256)][16B].
    // LDS dest is wave-uniform (i*1024); HW adds lane*16; source decoded per-lane.
    unsigned int vdiff = (unsigned int)(VT_b - Kp_b);
    unsigned int soff[7], smul[7];
#pragma unroll
    for (int j = 0; j < 7; j++) {
        int i = wave + 4 * j;
        int d = i * 1024 + lane * 16;
        if (i < 10) {
            int kc = d >> 11, slot = (d >> 9) & 3, row = (d >> 4) & 31;
            soff[j] = row * KP + kc * 32 + slot * 8;
            smul[j] = KP;      // per-chunk advance: ln*KP
        } else {
            int d2 = d - 10240;
            int slot = d2 >> 12, c = (d2 >> 4) & 255;
            soff[j] = vdiff + c * LP + slot * 8;
            smul[j] = 1;       // per-chunk advance: ln
        }
    }
    int ncall = (wave < 2) ? 7 : 6;
    int dustart = wave * 1024;  // wave-uniform LDS dest base

    // F frags (f16): rows pw..pw+15 (A) and pw+16..pw+31 (B)
    f16x8 fA[5], fB[5];
    {
        size_t fbA = (size_t)(pw + l15) * KP + lq * 8;
        size_t fbB = (size_t)(pw + 16 + l15) * KP + lq * 8;
#pragma unroll
        for (int kc = 0; kc < 5; kc++) {
            fA[kc] = *(const f16x8*)&Fp_b[fbA + kc * 32];
            fB[kc] = *(const f16x8*)&Fp_b[fbB + kc * 32];
        }
    }

    f32x4 zero4 = {0.f, 0.f, 0.f, 0.f};
    f32x4 accA[16], accB[16];
#pragma unroll
    for (int n = 0; n < 16; n++) { accA[n] = zero4; accB[n] = zero4; }
    float dA[4] = {0.f, 0.f, 0.f, 0.f};
    float dB[4] = {0.f, 0.f, 0.f, 0.f};

    // prologue: stage chunk 0 into buf 0
#pragma unroll
    for (int j = 0; j < 7; j++)
        if (j < ncall)
            gl_lds16(Kp_b + soff[j] + (size_t)lbase * smul[j], &S_lds[0][dustart + j * 4096]);

    for (int ch = 0; ch < NCH; ch++) {
        int cur = ch & 1;
        int l0 = lbase + ch * 32;
        __syncthreads();   // drains staging of buf[cur] (vmcnt0) + fences reads

        float mmh0 = mm_b[l0 + l15];
        float mmh1 = mm_b[l0 + 16 + l15];

        if (ch + 1 < NCH) {
            size_t ln = (size_t)(l0 + 32);
#pragma unroll
            for (int j = 0; j < 7; j++)
                if (j < ncall)
                    gl_lds16(Kp_b + soff[j] + ln * smul[j], &S_lds[cur ^ 1][dustart + j * 4096]);
        }

        // ---- S phase: f16 single-pass; K frag reused by both row-halves
        float eA[2][4], eB[2][4];
#pragma unroll
        for (int h = 0; h < 2; h++) {
            const char* kb = &S_lds[cur][lq * 512 + (h * 16 + l15) * 16];
            f32x4 sA = zero4, sB = zero4;
#pragma unroll
            for (int kc = 0; kc < 5; kc++) {
                f16x8 kv = *(const f16x8*)(kb + kc * 2048);
                sA = __builtin_amdgcn_mfma_f32_16x16x32_f16(fA[kc], kv, sA, 0, 0, 0);
                sB = __builtin_amdgcn_mfma_f32_16x16x32_f16(fB[kc], kv, sB, 0, 0, 0);
            }
            float mmh = h ? mmh1 : mmh0;
#pragma unroll
            for (int r = 0; r < 4; r++) {
                float zA = (mmh > 0.f) ? 10.f * sA[r] : 0.f;
                float zB = (mmh > 0.f) ? 10.f * sB[r] : 0.f;
                float ea = __expf(zA - 60.f);
                float eb = __expf(zB - 60.f);
                dA[r] += ea; dB[r] += eb;
                eA[h][r] = ea * mmh; eB[h][r] = eb * mmh;
            }
        }

        // ---- P tiles (bf16): D-frag -> [p][l] per-wave LDS, read as A-frag
#pragma unroll
        for (int h = 0; h < 2; h++)
#pragma unroll
            for (int r = 0; r < 4; r++) {
                P_lds[wave][0][lq * 4 + r][h * 16 + l15] = pack_rne(eA[h][r]);
                P_lds[wave][1][lq * 4 + r][h * 16 + l15] = pack_rne(eB[h][r]);
            }
        bf16x8 pa0 = *(const bf16x8*)&P_lds[wave][0][l15][lq * 8];
        bf16x8 pa1 = *(const bf16x8*)&P_lds[wave][1][l15][lq * 8];

        // ---- O phase: 16 c-tiles; V frag reused by both row-halves
        const char* Vc = &S_lds[cur][10240 + lq * 4096];
#pragma unroll
        for (int g = 0; g < 4; g++) {
            bf16x8 vb[4];
#pragma unroll
            for (int nn = 0; nn < 4; nn++)
                vb[nn] = *(const bf16x8*)(Vc + (g * 64 + nn * 16 + l15) * 16);
#pragma unroll
            for (int nn = 0; nn < 4; nn++) {
                accA[g * 4 + nn] = __builtin_amdgcn_mfma_f32_16x16x32_bf16(pa0, vb[nn], accA[g * 4 + nn], 0, 0, 0);
                accB[g * 4 + nn] = __builtin_amdgcn_mfma_f32_16x16x32_bf16(pa1, vb[nn], accB[g * 4 + nn], 0, 0, 0);
            }
        }
    }

    // ---- epilogue: finish partial denoms across the 16 lanes of each row
#pragma unroll
    for (int s = 1; s < 16; s <<= 1)
#pragma unroll
        for (int r = 0; r < 4; r++) {
            dA[r] += __shfl_xor(dA[r], s);
            dB[r] += __shfl_xor(dB[r], s);
        }

    if (l15 == 0) {
        float* dp = Dp + ((size_t)sp * BB + b) * LP;
#pragma unroll
        for (int r = 0; r < 4; r++) {
            dp[pw + lq * 4 + r] = dA[r];
            dp[pw + 16 + lq * 4 + r] = dB[r];
        }
    }
    float* Uo = Up + ((size_t)sp * BB + b) * LP * N2;
#pragma unroll
    for (int g = 0; g < 4; g++)
#pragma unroll
        for (int nn = 0; nn < 4; nn++) {
            int col = g * 64 + nn * 16 + l15;
#pragma unroll
            for (int r = 0; r < 4; r++) {
                Uo[(size_t)(pw + lq * 4 + r) * N2 + col] = accA[g * 4 + nn][r];
                Uo[(size_t)(pw + 16 + lq * 4 + r) * N2 + col] = accB[g * 4 + nn][r];
            }
        }
}

// ---------------------------------------------------------------------------
// merge: U = (sum_sp Up) / (sum_sp Dp). Streaming, one row per block.
// ---------------------------------------------------------------------------
__global__ __launch_bounds__(256) void merge_kernel(
    const float* __restrict__ Up, const float* __restrict__ Dp,
    float* __restrict__ U)
{
    size_t row = blockIdx.x;            // b*LP + p
    int c = threadIdx.x;
    float d = 0.f, a = 0.f;
#pragma unroll
    for (int s = 0; s < NS; s++) {
        d += Dp[(size_t)s * BB * LP + row];
        a += Up[((size_t)s * BB * LP + row) * N2 + c];
    }
    U[row * N2 + c] = a / d;
}

// ---------------------------------------------------------------------------
// gather / overlap-add (upright), fp32 out
// ---------------------------------------------------------------------------
__global__ __launch_bounds__(256) void gather_kernel(
    const float* __restrict__ U, float* __restrict__ out)
{
    int idx = blockIdx.x * 256 + threadIdx.x;
    int ox = idx & 127;
    int t1 = idx >> 7;
    int oy = t1 & 127;
    int t2 = t1 >> 7;
    int c = t2 & 15;
    int b = t2 >> 4;

    float sum = 0.f;
    int d0y = (oy + 1) & 1, d0x = (ox + 1) & 1;
#pragma unroll
    for (int iy = 0; iy < 2; iy++) {
        int dy = d0y + 2 * iy;
        int y = (oy + 1 - dy) >> 1;
        if (y < 0 || y > 63) continue;
#pragma unroll
        for (int ix = 0; ix < 2; ix++) {
            int dx = d0x + 2 * ix;
            int x = (ox + 1 - dx) >> 1;
            if (x < 0 || x > 63) continue;
            sum += U[((long)b * LP + y * 64 + x) * N2 + c * 16 + dy * 4 + dx];
        }
    }
    out[idx] = sum * 0.25f;
}

// ---------------------------------------------------------------------------
extern "C" void kernel_launch(void* const* d_in, const int* in_sizes, int n_in,
                              void* d_out, int out_size, void* d_ws, size_t ws_size,
                              hipStream_t stream)
{
    const void* fg   = d_in[0];
    const void* bg   = d_in[1];
    const void* mask = d_in[2];
    float* out = (float*)d_out;

    char* w = (char*)d_ws;
    size_t o = 0;
    int*            flag = (int*)(w + o);            o += 16;
    unsigned short* Fp   = (unsigned short*)(w + o); o += (size_t)BB * LP * KP * 2;
    unsigned short* Kp   = (unsigned short*)(w + o); o += (size_t)BB * LP * KP * 2;
    unsigned short* VT   = (unsigned short*)(w + o); o += (size_t)BB * N2 * LP * 2;  // must follow Kp (vdiff u32)
    float*          U    = (float*)(w + o);          o += (size_t)BB * LP * N2 * 4;
    float*          mmg  = (float*)(w + o);          o += (size_t)BB * LP * 4;
    float*          Dp   = (float*)(w + o);          o += (size_t)NS * BB * LP * 4;
    float*          Up   = (float*)(w + o);          o += (size_t)NS * BB * LP * N2 * 4;

    detect_kernel<<<1, 64, 0, stream>>>((const unsigned int*)fg, flag);
    prep_kernel<<<BB * LP / 4, 256, 0, stream>>>(fg, bg, mask, flag, Fp, Kp, mmg);
    vT_kernel<<<dim3(LP / 16, BB), 256, 0, stream>>>(bg, flag, VT);

    flash_kernel<<<dim3(LP / 128, NS, BB), 256, 0, stream>>>(Fp, Kp, VT, mmg, Up, Dp);
    merge_kernel<<<BB * LP, 256, 0, stream>>>(Up, Dp, U);

    gather_kernel<<<(BB * CC * HH * WW) / 256, 256, 0, stream>>>(U, out);
}

// Round 10
// 160.199 us; speedup vs baseline: 9.0886x; 1.9455x over previous
//
#include <hip/hip_runtime.h>
#include <hip/hip_bf16.h>
#include <hip/hip_fp16.h>

#define BB 8
#define CC 16
#define HH 128
#define WW 128
#define HD 64
#define WD 64
#define LP 4096
#define K1 144
#define KP 160
#define N2 256
#define E60 8.75651076269652e-27f   // exp(-60)

typedef __attribute__((ext_vector_type(8))) short bf16x8;
typedef __attribute__((ext_vector_type(8))) _Float16 f16x8;
typedef __attribute__((ext_vector_type(4))) float f32x4;

__device__ __forceinline__ unsigned short pack_rne(float x) {
    unsigned int u = __float_as_uint(x);
    return (unsigned short)((u + 0x7FFFu + ((u >> 16) & 1u)) >> 16);
}
__device__ __forceinline__ float bf2f(unsigned short u) {
    return __uint_as_float(((unsigned int)u) << 16);
}
__device__ __forceinline__ unsigned short f2h(float x) {
    return __half_as_ushort(__float2half(x));   // RNE
}
__device__ __forceinline__ float ld_in(const void* p, long idx, int bf) {
    if (bf) return bf2f(((const unsigned short*)p)[idx]);
    return ((const float*)p)[idx];
}
__device__ __forceinline__ void gl_lds16(const void* g, void* l) {
    __builtin_amdgcn_global_load_lds(
        (const __attribute__((address_space(1))) unsigned int*)g,
        (__attribute__((address_space(3))) unsigned int*)l,
        16, 0, 0);
}

// ---------------------------------------------------------------------------
__global__ void detect_kernel(const unsigned int* __restrict__ w, int* __restrict__ flag) {
    if (threadIdx.x == 0) {
        int cnt = 0;
        for (int i = 0; i < 256; i++) {
            unsigned int e = (w[i] >> 7) & 0xFF;
            if (e >= 100 && e <= 140) cnt++;
        }
        *flag = (cnt >= 192) ? 1 : 0;
    }
}

// ---------------------------------------------------------------------------
// prep v3: one wave per patch; shuffle-butterfly reductions; f16 Fp/Kp.
// ---------------------------------------------------------------------------
__global__ __launch_bounds__(256) void prep_kernel(
    const void* __restrict__ fg, const void* __restrict__ bg,
    const void* __restrict__ mask, const int* __restrict__ flagp,
    unsigned short* __restrict__ Fp, unsigned short* __restrict__ Kp,
    float* __restrict__ mmg)
{
    int bf = *flagp;
    int wave = threadIdx.x >> 6, lane = threadIdx.x & 63;
    int bl = blockIdx.x * 4 + wave;
    int b = bl >> 12, l = bl & 4095;
    int py = l >> 6, px = l & 63;

    float fgv[3], bgv[3];
    float ss = 0.f;
#pragma unroll
    for (int j = 0; j < 3; j++) {
        int e = lane + 64 * j;
        fgv[j] = 0.f; bgv[j] = 0.f;
        if (e < K1) {
            int c = e / 9;
            int r9 = e - c * 9;
            int ky = r9 / 3, kx = r9 - ky * 3;
            int yy = py + ky - 1, xx = px + kx - 1;
            if (yy >= 0 && yy < HD && xx >= 0 && xx < WD) {
                long base = ((long)(b * CC + c) * HH + 2 * yy) * WW + 2 * xx;
                fgv[j] = ld_in(fg, base, bf);
                bgv[j] = ld_in(bg, base, bf);
            }
        }
        ss += bgv[j] * bgv[j];
    }
#pragma unroll
    for (int s = 1; s < 64; s <<= 1) ss += __shfl_xor(ss, s);
    float rn = 1.0f / fmaxf(sqrtf(ss), 1e-4f);

    float mv = 0.f;
    if (lane < 9) {
        int ky = lane / 3, kx = lane - ky * 3;
        int yy = py + ky - 1, xx = px + kx - 1;
        if (yy >= 0 && yy < HD && xx >= 0 && xx < WD)
            mv = ld_in(mask, ((long)b * HH + 2 * yy) * WW + 2 * xx, bf);
    }
#pragma unroll
    for (int s = 1; s < 16; s <<= 1) mv += __shfl_xor(mv, s);
    if (lane == 0) mmg[bl] = (mv == 0.0f) ? 1.0f : 0.0f;

    long base = (long)bl * KP;
#pragma unroll
    for (int j = 0; j < 3; j++) {
        int e = lane + 64 * j;
        if (e < KP) {
            Fp[base + e] = f2h(fgv[j]);          // 0 beyond K1 -> zero pad
            Kp[base + e] = f2h(bgv[j] * rn);
        }
    }
}

// ---------------------------------------------------------------------------
// compact1: ordered ballot-compaction of mm=1 column indices. One wave/batch.
// ---------------------------------------------------------------------------
__global__ __launch_bounds__(64) void compact1_kernel(
    const float* __restrict__ mmg, int* __restrict__ idx, int* __restrict__ cnt)
{
    int b = blockIdx.x;
    int lane = threadIdx.x;
    const float* mm = mmg + (size_t)b * LP;
    int* ib = idx + (size_t)b * LP;
    int base = 0;
    for (int i = 0; i < LP / 64; i++) {
        int l = i * 64 + lane;
        bool v = mm[l] > 0.f;
        unsigned long long m = __ballot(v);
        int off = __popcll(m & ((1ull << lane) - 1ull));
        if (v) ib[base + off] = l;
        base += __popcll(m);
    }
    if (lane == 0) cnt[b] = base;
}

// ---------------------------------------------------------------------------
// compact2: build compacted Kc[b][j][160] (row copy of Kp) and Vc[b][c][j]
// (vT math at l = idx[j]); zero-pad j in [cnt, roundup32(cnt)) -- V pad MUST
// be zero (P=0 x garbage-inf would NaN the O-MFMA).
// ---------------------------------------------------------------------------
__global__ __launch_bounds__(256) void compact2_kernel(
    const void* __restrict__ bg, const int* __restrict__ flagp,
    const unsigned short* __restrict__ Kp,
    const int* __restrict__ idx, const int* __restrict__ cnt,
    unsigned short* __restrict__ Kc, unsigned short* __restrict__ Vc)
{
    int bf = *flagp;
    int b = blockIdx.x;
    int n = cnt[b];
    int npad = (n + 31) & ~31;
    int t = threadIdx.x;
    int cch = t >> 4, dy = (t >> 2) & 3, dx = t & 3;   // VT row encoding

    for (int j = blockIdx.y; j < npad; j += 16) {
        unsigned short kv = 0, vv = 0;
        if (j < n) {
            int l = idx[(size_t)b * LP + j];
            if (t < KP) kv = Kp[((size_t)b * LP + l) * KP + t];
            int ly = l >> 6, lx = l & 63;
            int Y = 2 * ly + dy - 1, X = 2 * lx + dx - 1;
            float v = 0.f;
            if (Y >= 0 && Y < HH && X >= 0 && X < WW)
                v = ld_in(bg, ((long)(b * CC + cch) * HH + Y) * WW + X, bf);
            vv = pack_rne(v);
        }
        if (t < KP) Kc[((size_t)b * LP + j) * KP + t] = kv;
        Vc[((size_t)b * N2 + t) * LP + j] = vv;
    }
}

// ---------------------------------------------------------------------------
// flash v8 (sparse): identical inner machinery to r9 (verified), but sweeping
// only the COMPACTED columns: nch = ceil(cnt/32) chunks (~1 for this data vs
// 64 dense). mmh = (j < cnt); all mm=0 columns contribute exactly e^-60 to
// the denominator -> closed-form correction (4096 - 32*nch)*E60. Writes U
// directly (no split-l, no Up/Dp/merge). Worst case cnt=4096 degrades to the
// r9 full sweep. Grid (32 p-tiles, 8 batches).
// ---------------------------------------------------------------------------
__global__ __launch_bounds__(256, 2) void flash_kernel(
    const unsigned short* __restrict__ Fp, const unsigned short* __restrict__ Kc,
    const unsigned short* __restrict__ Vc,  // [BB][256][4096] bf16 compacted
    const int* __restrict__ cnt,
    float* __restrict__ U)                  // [BB][4096][256]
{
    __shared__ char S_lds[2][26624];                // [K 10240 | V 16384]
    __shared__ unsigned short P_lds[4][2][16][40];  // per-wave, per-row-half

    int t = threadIdx.x;
    int wave = t >> 6, lane = t & 63;
    int l15 = lane & 15, lq = lane >> 4;

    int b = blockIdx.y;
    int pw = blockIdx.x * 128 + wave * 32;

    const unsigned short* Fp_b = Fp + (size_t)b * LP * KP;
    const unsigned short* Kc_b = Kc + (size_t)b * LP * KP;
    const unsigned short* Vc_b = Vc + (size_t)b * N2 * LP;

    int n = cnt[b];
    int nch = (n + 31) >> 5;

    // staging maps (identical to r9): 26 x 1KB calls, call i by wave i%4.
    unsigned int vdiff = (unsigned int)(Vc_b - Kc_b);
    unsigned int soff[7], smul[7];
#pragma unroll
    for (int j = 0; j < 7; j++) {
        int i = wave + 4 * j;
        int d = i * 1024 + lane * 16;
        if (i < 10) {
            int kc = d >> 11, slot = (d >> 9) & 3, row = (d >> 4) & 31;
            soff[j] = row * KP + kc * 32 + slot * 8;
            smul[j] = KP;
        } else {
            int d2 = d - 10240;
            int slot = d2 >> 12, c = (d2 >> 4) & 255;
            soff[j] = vdiff + c * LP + slot * 8;
            smul[j] = 1;
        }
    }
    int ncall = (wave < 2) ? 7 : 6;
    int dustart = wave * 1024;

    // F frags (f16): rows pw..pw+15 (A) and pw+16..pw+31 (B)
    f16x8 fA[5], fB[5];
    {
        size_t fbA = (size_t)(pw + l15) * KP + lq * 8;
        size_t fbB = (size_t)(pw + 16 + l15) * KP + lq * 8;
#pragma unroll
        for (int kc = 0; kc < 5; kc++) {
            fA[kc] = *(const f16x8*)&Fp_b[fbA + kc * 32];
            fB[kc] = *(const f16x8*)&Fp_b[fbB + kc * 32];
        }
    }

    f32x4 zero4 = {0.f, 0.f, 0.f, 0.f};
    f32x4 accA[16], accB[16];
#pragma unroll
    for (int nn = 0; nn < 16; nn++) { accA[nn] = zero4; accB[nn] = zero4; }
    float dA[4] = {0.f, 0.f, 0.f, 0.f};
    float dB[4] = {0.f, 0.f, 0.f, 0.f};

    if (nch > 0) {
#pragma unroll
        for (int j = 0; j < 7; j++)
            if (j < ncall)
                gl_lds16(Kc_b + soff[j], &S_lds[0][dustart + j * 4096]);
    }

    for (int ch = 0; ch < nch; ch++) {
        int cur = ch & 1;
        int l0 = ch * 32;
        __syncthreads();   // drains staging of buf[cur] + fences prev reads

        float mmh0 = (l0 + l15 < n) ? 1.f : 0.f;
        float mmh1 = (l0 + 16 + l15 < n) ? 1.f : 0.f;

        if (ch + 1 < nch) {
            size_t ln = (size_t)(l0 + 32);
#pragma unroll
            for (int j = 0; j < 7; j++)
                if (j < ncall)
                    gl_lds16(Kc_b + soff[j] + ln * smul[j], &S_lds[cur ^ 1][dustart + j * 4096]);
        }

        // ---- S phase: f16 single-pass; K frag reused by both row-halves
        float eA[2][4], eB[2][4];
#pragma unroll
        for (int h = 0; h < 2; h++) {
            const char* kb = &S_lds[cur][lq * 512 + (h * 16 + l15) * 16];
            f32x4 sA = zero4, sB = zero4;
#pragma unroll
            for (int kc = 0; kc < 5; kc++) {
                f16x8 kv = *(const f16x8*)(kb + kc * 2048);
                sA = __builtin_amdgcn_mfma_f32_16x16x32_f16(fA[kc], kv, sA, 0, 0, 0);
                sB = __builtin_amdgcn_mfma_f32_16x16x32_f16(fB[kc], kv, sB, 0, 0, 0);
            }
            float mmh = h ? mmh1 : mmh0;
#pragma unroll
            for (int r = 0; r < 4; r++) {
                float zA = (mmh > 0.f) ? 10.f * sA[r] : 0.f;
                float zB = (mmh > 0.f) ? 10.f * sB[r] : 0.f;
                float ea = __expf(zA - 60.f);
                float eb = __expf(zB - 60.f);
                dA[r] += ea; dB[r] += eb;
                eA[h][r] = ea * mmh; eB[h][r] = eb * mmh;
            }
        }

        // ---- P tiles (bf16): D-frag -> [p][l] per-wave LDS, read as A-frag
#pragma unroll
        for (int h = 0; h < 2; h++)
#pragma unroll
            for (int r = 0; r < 4; r++) {
                P_lds[wave][0][lq * 4 + r][h * 16 + l15] = pack_rne(eA[h][r]);
                P_lds[wave][1][lq * 4 + r][h * 16 + l15] = pack_rne(eB[h][r]);
            }
        bf16x8 pa0 = *(const bf16x8*)&P_lds[wave][0][l15][lq * 8];
        bf16x8 pa1 = *(const bf16x8*)&P_lds[wave][1][l15][lq * 8];

        // ---- O phase: 16 c-tiles; V frag reused by both row-halves
        const char* Vcp = &S_lds[cur][10240 + lq * 4096];
#pragma unroll
        for (int g = 0; g < 4; g++) {
            bf16x8 vb[4];
#pragma unroll
            for (int nn = 0; nn < 4; nn++)
                vb[nn] = *(const bf16x8*)(Vcp + (g * 64 + nn * 16 + l15) * 16);
#pragma unroll
            for (int nn = 0; nn < 4; nn++) {
                accA[g * 4 + nn] = __builtin_amdgcn_mfma_f32_16x16x32_bf16(pa0, vb[nn], accA[g * 4 + nn], 0, 0, 0);
                accB[g * 4 + nn] = __builtin_amdgcn_mfma_f32_16x16x32_bf16(pa1, vb[nn], accB[g * 4 + nn], 0, 0, 0);
            }
        }
    }

    // ---- epilogue: denom across the 16 lanes + closed-form mm=0 correction
#pragma unroll
    for (int s = 1; s < 16; s <<= 1)
#pragma unroll
        for (int r = 0; r < 4; r++) {
            dA[r] += __shfl_xor(dA[r], s);
            dB[r] += __shfl_xor(dB[r], s);
        }
    float corr = (float)(LP - nch * 32) * E60;
    float diA[4], diB[4];
#pragma unroll
    for (int r = 0; r < 4; r++) {
        diA[r] = 1.0f / (dA[r] + corr);
        diB[r] = 1.0f / (dB[r] + corr);
    }

    float* Uo = U + (size_t)b * LP * N2;
#pragma unroll
    for (int g = 0; g < 4; g++)
#pragma unroll
        for (int nn = 0; nn < 4; nn++) {
            int col = g * 64 + nn * 16 + l15;
#pragma unroll
            for (int r = 0; r < 4; r++) {
                Uo[(size_t)(pw + lq * 4 + r) * N2 + col] = accA[g * 4 + nn][r] * diA[r];
                Uo[(size_t)(pw + 16 + lq * 4 + r) * N2 + col] = accB[g * 4 + nn][r] * diB[r];
            }
        }
}

// ---------------------------------------------------------------------------
// gather / overlap-add (upright), fp32 out
// ---------------------------------------------------------------------------
__global__ __launch_bounds__(256) void gather_kernel(
    const float* __restrict__ U, float* __restrict__ out)
{
    int idx = blockIdx.x * 256 + threadIdx.x;
    int ox = idx & 127;
    int t1 = idx >> 7;
    int oy = t1 & 127;
    int t2 = t1 >> 7;
    int c = t2 & 15;
    int b = t2 >> 4;

    float sum = 0.f;
    int d0y = (oy + 1) & 1, d0x = (ox + 1) & 1;
#pragma unroll
    for (int iy = 0; iy < 2; iy++) {
        int dy = d0y + 2 * iy;
        int y = (oy + 1 - dy) >> 1;
        if (y < 0 || y > 63) continue;
#pragma unroll
        for (int ix = 0; ix < 2; ix++) {
            int dx = d0x + 2 * ix;
            int x = (ox + 1 - dx) >> 1;
            if (x < 0 || x > 63) continue;
            sum += U[((long)b * LP + y * 64 + x) * N2 + c * 16 + dy * 4 + dx];
        }
    }
    out[idx] = sum * 0.25f;
}

// ---------------------------------------------------------------------------
extern "C" void kernel_launch(void* const* d_in, const int* in_sizes, int n_in,
                              void* d_out, int out_size, void* d_ws, size_t ws_size,
                              hipStream_t stream)
{
    const void* fg   = d_in[0];
    const void* bg   = d_in[1];
    const void* mask = d_in[2];
    float* out = (float*)d_out;

    char* w = (char*)d_ws;
    size_t o = 0;
    int*            flag = (int*)(w + o);            o += 16;
    int*            cnt  = (int*)(w + o);            o += 64;
    unsigned short* Fp   = (unsigned short*)(w + o); o += (size_t)BB * LP * KP * 2;
    unsigned short* Kp   = (unsigned short*)(w + o); o += (size_t)BB * LP * KP * 2;
    unsigned short* Kc   = (unsigned short*)(w + o); o += (size_t)BB * LP * KP * 2;
    unsigned short* Vc   = (unsigned short*)(w + o); o += (size_t)BB * N2 * LP * 2;  // must follow Kc (vdiff u32)
    float*          U    = (float*)(w + o);          o += (size_t)BB * LP * N2 * 4;
    float*          mmg  = (float*)(w + o);          o += (size_t)BB * LP * 4;
    int*            idx  = (int*)(w + o);            o += (size_t)BB * LP * 4;

    detect_kernel<<<1, 64, 0, stream>>>((const unsigned int*)fg, flag);
    prep_kernel<<<BB * LP / 4, 256, 0, stream>>>(fg, bg, mask, flag, Fp, Kp, mmg);
    compact1_kernel<<<BB, 64, 0, stream>>>(mmg, idx, cnt);
    compact2_kernel<<<dim3(BB, 16), 256, 0, stream>>>(bg, flag, Kp, idx, cnt, Kc, Vc);

    flash_kernel<<<dim3(LP / 128, BB), 256, 0, stream>>>(Fp, Kc, Vc, cnt, U);

    gather_kernel<<<(BB * CC * HH * WW) / 256, 256, 0, stream>>>(U, out);
}

// Round 11
// 129.670 us; speedup vs baseline: 11.2283x; 1.2354x over previous
//
#include <hip/hip_runtime.h>
#include <hip/hip_bf16.h>
#include <hip/hip_fp16.h>

#define BB 8
#define CC 16
#define HH 128
#define WW 128
#define HD 64
#define WD 64
#define LP 4096
#define K1 144
#define KP 160
#define N2 256
#define E60 8.75651076269652e-27f   // exp(-60)

typedef __attribute__((ext_vector_type(8))) short bf16x8;
typedef __attribute__((ext_vector_type(8))) _Float16 f16x8;
typedef __attribute__((ext_vector_type(4))) float f32x4;

__device__ __forceinline__ unsigned short pack_rne(float x) {
    unsigned int u = __float_as_uint(x);
    return (unsigned short)((u + 0x7FFFu + ((u >> 16) & 1u)) >> 16);
}
__device__ __forceinline__ float bf2f(unsigned short u) {
    return __uint_as_float(((unsigned int)u) << 16);
}
__device__ __forceinline__ unsigned short f2h(float x) {
    return __half_as_ushort(__float2half(x));   // RNE
}
__device__ __forceinline__ float ld_in(const void* p, long idx, int bf) {
    if (bf) return bf2f(((const unsigned short*)p)[idx]);
    return ((const float*)p)[idx];
}
__device__ __forceinline__ void gl_lds16(const void* g, void* l) {
    __builtin_amdgcn_global_load_lds(
        (const __attribute__((address_space(1))) unsigned int*)g,
        (__attribute__((address_space(3))) unsigned int*)l,
        16, 0, 0);
}

// ---------------------------------------------------------------------------
// detect (lane-parallel) + zero the per-batch compaction counters.
// ---------------------------------------------------------------------------
__global__ void detect_kernel(const unsigned int* __restrict__ w,
                              int* __restrict__ flag, int* __restrict__ cnt) {
    int lane = threadIdx.x;
    if (lane < BB) cnt[lane] = 0;
    int c = 0;
    for (int i = lane; i < 256; i += 64) {
        unsigned int e = (w[i] >> 7) & 0xFF;
        if (e >= 100 && e <= 140) c++;
    }
#pragma unroll
    for (int s = 1; s < 64; s <<= 1) c += __shfl_xor(c, s);
    if (lane == 0) *flag = (c >= 192) ? 1 : 0;
}

// ---------------------------------------------------------------------------
// prep v5: one wave per patch; writes Fp (all patches) AND, for mm=1 patches,
// directly compacts: slot j = atomicAdd(cnt[b]) (column ORDER is irrelevant --
// U = sum_j P_j V_j and the denom are order-independent), then writes the
// Kc row (f16, normalized) and the Vc column (bf16, 256 bg loads).
// Removes compact1/compact2/Kp entirely.
// ---------------------------------------------------------------------------
__global__ __launch_bounds__(256) void prep_kernel(
    const void* __restrict__ fg, const void* __restrict__ bg,
    const void* __restrict__ mask, const int* __restrict__ flagp,
    unsigned short* __restrict__ Fp, int* __restrict__ cnt,
    unsigned short* __restrict__ Kc, unsigned short* __restrict__ Vc)
{
    int bf = *flagp;
    int wave = threadIdx.x >> 6, lane = threadIdx.x & 63;
    int bl = blockIdx.x * 4 + wave;
    int b = bl >> 12, l = bl & 4095;
    int py = l >> 6, px = l & 63;

    float fgv[3], bgv[3];
    float ss = 0.f;
#pragma unroll
    for (int j = 0; j < 3; j++) {
        int e = lane + 64 * j;
        fgv[j] = 0.f; bgv[j] = 0.f;
        if (e < K1) {
            int c = e / 9;
            int r9 = e - c * 9;
            int ky = r9 / 3, kx = r9 - ky * 3;
            int yy = py + ky - 1, xx = px + kx - 1;
            if (yy >= 0 && yy < HD && xx >= 0 && xx < WD) {
                long base = ((long)(b * CC + c) * HH + 2 * yy) * WW + 2 * xx;
                fgv[j] = ld_in(fg, base, bf);
                bgv[j] = ld_in(bg, base, bf);
            }
        }
        ss += bgv[j] * bgv[j];
    }
#pragma unroll
    for (int s = 1; s < 64; s <<= 1) ss += __shfl_xor(ss, s);
    float rn = 1.0f / fmaxf(sqrtf(ss), 1e-4f);

    // mask: all-9-zero test
    float mv = 0.f;
    if (lane < 9) {
        int ky = lane / 3, kx = lane - ky * 3;
        int yy = py + ky - 1, xx = px + kx - 1;
        if (yy >= 0 && yy < HD && xx >= 0 && xx < WD)
            mv = ld_in(mask, ((long)b * HH + 2 * yy) * WW + 2 * xx, bf);
    }
#pragma unroll
    for (int s = 1; s < 16; s <<= 1) mv += __shfl_xor(mv, s);
    float mvall = __shfl(mv, 0);

    // Fp for all patches (f16, zero-padded to KP)
    long base = (long)bl * KP;
#pragma unroll
    for (int j = 0; j < 3; j++) {
        int e = lane + 64 * j;
        if (e < KP) Fp[base + e] = f2h(fgv[j]);
    }

    if (mvall == 0.0f) {
        int j0;
        if (lane == 0) j0 = atomicAdd(&cnt[b], 1);
        int j = __shfl(j0, 0);
        // Kc row (f16 normalized, zero-padded to KP)
        size_t kb = ((size_t)b * LP + j) * KP;
#pragma unroll
        for (int q = 0; q < 3; q++) {
            int e = lane + 64 * q;
            if (e < KP) Kc[kb + e] = f2h(bgv[q] * rn);
        }
        // Vc column: e = c*16 + dy*4 + dx, 4 per lane
        unsigned short* vcb = Vc + (size_t)b * N2 * LP + j;
#pragma unroll
        for (int q = 0; q < 4; q++) {
            int e = lane + 64 * q;
            int c = e >> 4, dy = (e >> 2) & 3, dx = e & 3;
            int Y = 2 * py + dy - 1, X = 2 * px + dx - 1;
            float v = 0.f;
            if (Y >= 0 && Y < HH && X >= 0 && X < WW)
                v = ld_in(bg, ((long)(b * CC + c) * HH + Y) * WW + X, bf);
            vcb[(size_t)e * LP] = pack_rne(v);
        }
    }
}

// ---------------------------------------------------------------------------
// zpad: zero Vc pad columns [n, roundup32(n)) -- mandatory (P=0 x poison-NaN
// would NaN the O-MFMA). Kc pad is provably harmless (z gated to 0 by j<n).
// ---------------------------------------------------------------------------
__global__ __launch_bounds__(256) void zpad_kernel(
    const int* __restrict__ cnt, unsigned short* __restrict__ Vc)
{
    int b = blockIdx.x;
    int n = cnt[b];
    int npad = (n + 31) & ~31;
    unsigned short* row = Vc + ((size_t)b * N2 + threadIdx.x) * LP;
    for (int j = n; j < npad; j++) row[j] = 0;
}

// ---------------------------------------------------------------------------
// flash v9 (sparse): r10 machinery (verified), U output now bf16.
// nch = ceil(cnt/32) chunks (~1 for this data); mmh = (j < cnt); closed-form
// denom correction (4096 - 32*nch)*E60. Grid (32 p-tiles, 8 batches).
// ---------------------------------------------------------------------------
__global__ __launch_bounds__(256, 2) void flash_kernel(
    const unsigned short* __restrict__ Fp, const unsigned short* __restrict__ Kc,
    const unsigned short* __restrict__ Vc,  // [BB][256][4096] bf16 compacted
    const int* __restrict__ cnt,
    unsigned short* __restrict__ U)         // [BB][4096][256] bf16
{
    __shared__ char S_lds[2][26624];                // [K 10240 | V 16384]
    __shared__ unsigned short P_lds[4][2][16][40];  // per-wave, per-row-half

    int t = threadIdx.x;
    int wave = t >> 6, lane = t & 63;
    int l15 = lane & 15, lq = lane >> 4;

    int b = blockIdx.y;
    int pw = blockIdx.x * 128 + wave * 32;

    const unsigned short* Fp_b = Fp + (size_t)b * LP * KP;
    const unsigned short* Kc_b = Kc + (size_t)b * LP * KP;
    const unsigned short* Vc_b = Vc + (size_t)b * N2 * LP;

    int n = cnt[b];
    int nch = (n + 31) >> 5;

    // staging maps: 26 x 1KB calls, call i by wave i%4.
    unsigned int vdiff = (unsigned int)(Vc_b - Kc_b);
    unsigned int soff[7], smul[7];
#pragma unroll
    for (int j = 0; j < 7; j++) {
        int i = wave + 4 * j;
        int d = i * 1024 + lane * 16;
        if (i < 10) {
            int kc = d >> 11, slot = (d >> 9) & 3, row = (d >> 4) & 31;
            soff[j] = row * KP + kc * 32 + slot * 8;
            smul[j] = KP;
        } else {
            int d2 = d - 10240;
            int slot = d2 >> 12, c = (d2 >> 4) & 255;
            soff[j] = vdiff + c * LP + slot * 8;
            smul[j] = 1;
        }
    }
    int ncall = (wave < 2) ? 7 : 6;
    int dustart = wave * 1024;

    // F frags (f16): rows pw..pw+15 (A) and pw+16..pw+31 (B)
    f16x8 fA[5], fB[5];
    {
        size_t fbA = (size_t)(pw + l15) * KP + lq * 8;
        size_t fbB = (size_t)(pw + 16 + l15) * KP + lq * 8;
#pragma unroll
        for (int kc = 0; kc < 5; kc++) {
            fA[kc] = *(const f16x8*)&Fp_b[fbA + kc * 32];
            fB[kc] = *(const f16x8*)&Fp_b[fbB + kc * 32];
        }
    }

    f32x4 zero4 = {0.f, 0.f, 0.f, 0.f};
    f32x4 accA[16], accB[16];
#pragma unroll
    for (int nn = 0; nn < 16; nn++) { accA[nn] = zero4; accB[nn] = zero4; }
    float dA[4] = {0.f, 0.f, 0.f, 0.f};
    float dB[4] = {0.f, 0.f, 0.f, 0.f};

    if (nch > 0) {
#pragma unroll
        for (int j = 0; j < 7; j++)
            if (j < ncall)
                gl_lds16(Kc_b + soff[j], &S_lds[0][dustart + j * 4096]);
    }

    for (int ch = 0; ch < nch; ch++) {
        int cur = ch & 1;
        int l0 = ch * 32;
        __syncthreads();   // drains staging of buf[cur] + fences prev reads

        float mmh0 = (l0 + l15 < n) ? 1.f : 0.f;
        float mmh1 = (l0 + 16 + l15 < n) ? 1.f : 0.f;

        if (ch + 1 < nch) {
            size_t ln = (size_t)(l0 + 32);
#pragma unroll
            for (int j = 0; j < 7; j++)
                if (j < ncall)
                    gl_lds16(Kc_b + soff[j] + ln * smul[j], &S_lds[cur ^ 1][dustart + j * 4096]);
        }

        // ---- S phase: f16 single-pass; K frag reused by both row-halves
        float eA[2][4], eB[2][4];
#pragma unroll
        for (int h = 0; h < 2; h++) {
            const char* kb = &S_lds[cur][lq * 512 + (h * 16 + l15) * 16];
            f32x4 sA = zero4, sB = zero4;
#pragma unroll
            for (int kc = 0; kc < 5; kc++) {
                f16x8 kv = *(const f16x8*)(kb + kc * 2048);
                sA = __builtin_amdgcn_mfma_f32_16x16x32_f16(fA[kc], kv, sA, 0, 0, 0);
                sB = __builtin_amdgcn_mfma_f32_16x16x32_f16(fB[kc], kv, sB, 0, 0, 0);
            }
            float mmh = h ? mmh1 : mmh0;
#pragma unroll
            for (int r = 0; r < 4; r++) {
                float zA = (mmh > 0.f) ? 10.f * sA[r] : 0.f;
                float zB = (mmh > 0.f) ? 10.f * sB[r] : 0.f;
                float ea = __expf(zA - 60.f);
                float eb = __expf(zB - 60.f);
                dA[r] += ea; dB[r] += eb;
                eA[h][r] = ea * mmh; eB[h][r] = eb * mmh;
            }
        }

        // ---- P tiles (bf16): D-frag -> [p][l] per-wave LDS, read as A-frag
#pragma unroll
        for (int h = 0; h < 2; h++)
#pragma unroll
            for (int r = 0; r < 4; r++) {
                P_lds[wave][0][lq * 4 + r][h * 16 + l15] = pack_rne(eA[h][r]);
                P_lds[wave][1][lq * 4 + r][h * 16 + l15] = pack_rne(eB[h][r]);
            }
        bf16x8 pa0 = *(const bf16x8*)&P_lds[wave][0][l15][lq * 8];
        bf16x8 pa1 = *(const bf16x8*)&P_lds[wave][1][l15][lq * 8];

        // ---- O phase: 16 c-tiles; V frag reused by both row-halves
        const char* Vcp = &S_lds[cur][10240 + lq * 4096];
#pragma unroll
        for (int g = 0; g < 4; g++) {
            bf16x8 vb[4];
#pragma unroll
            for (int nn = 0; nn < 4; nn++)
                vb[nn] = *(const bf16x8*)(Vcp + (g * 64 + nn * 16 + l15) * 16);
#pragma unroll
            for (int nn = 0; nn < 4; nn++) {
                accA[g * 4 + nn] = __builtin_amdgcn_mfma_f32_16x16x32_bf16(pa0, vb[nn], accA[g * 4 + nn], 0, 0, 0);
                accB[g * 4 + nn] = __builtin_amdgcn_mfma_f32_16x16x32_bf16(pa1, vb[nn], accB[g * 4 + nn], 0, 0, 0);
            }
        }
    }

    // ---- epilogue: denom across the 16 lanes + closed-form mm=0 correction
#pragma unroll
    for (int s = 1; s < 16; s <<= 1)
#pragma unroll
        for (int r = 0; r < 4; r++) {
            dA[r] += __shfl_xor(dA[r], s);
            dB[r] += __shfl_xor(dB[r], s);
        }
    float corr = (float)(LP - nch * 32) * E60;
    float diA[4], diB[4];
#pragma unroll
    for (int r = 0; r < 4; r++) {
        diA[r] = 1.0f / (dA[r] + corr);
        diB[r] = 1.0f / (dB[r] + corr);
    }

    unsigned short* Uo = U + (size_t)b * LP * N2;
#pragma unroll
    for (int g = 0; g < 4; g++)
#pragma unroll
        for (int nn = 0; nn < 4; nn++) {
            int col = g * 64 + nn * 16 + l15;
#pragma unroll
            for (int r = 0; r < 4; r++) {
                Uo[(size_t)(pw + lq * 4 + r) * N2 + col] = pack_rne(accA[g * 4 + nn][r] * diA[r]);
                Uo[(size_t)(pw + 16 + lq * 4 + r) * N2 + col] = pack_rne(accB[g * 4 + nn][r] * diB[r]);
            }
        }
}

// ---------------------------------------------------------------------------
// gather / overlap-add (upright), bf16 U -> fp32 out
// ---------------------------------------------------------------------------
__global__ __launch_bounds__(256) void gather_kernel(
    const unsigned short* __restrict__ U, float* __restrict__ out)
{
    int idx = blockIdx.x * 256 + threadIdx.x;
    int ox = idx & 127;
    int t1 = idx >> 7;
    int oy = t1 & 127;
    int t2 = t1 >> 7;
    int c = t2 & 15;
    int b = t2 >> 4;

    float sum = 0.f;
    int d0y = (oy + 1) & 1, d0x = (ox + 1) & 1;
#pragma unroll
    for (int iy = 0; iy < 2; iy++) {
        int dy = d0y + 2 * iy;
        int y = (oy + 1 - dy) >> 1;
        if (y < 0 || y > 63) continue;
#pragma unroll
        for (int ix = 0; ix < 2; ix++) {
            int dx = d0x + 2 * ix;
            int x = (ox + 1 - dx) >> 1;
            if (x < 0 || x > 63) continue;
            sum += bf2f(U[((long)b * LP + y * 64 + x) * N2 + c * 16 + dy * 4 + dx]);
        }
    }
    out[idx] = sum * 0.25f;
}

// ---------------------------------------------------------------------------
extern "C" void kernel_launch(void* const* d_in, const int* in_sizes, int n_in,
                              void* d_out, int out_size, void* d_ws, size_t ws_size,
                              hipStream_t stream)
{
    const void* fg   = d_in[0];
    const void* bg   = d_in[1];
    const void* mask = d_in[2];
    float* out = (float*)d_out;

    char* w = (char*)d_ws;
    size_t o = 0;
    int*            flag = (int*)(w + o);            o += 16;
    int*            cnt  = (int*)(w + o);            o += 64;
    unsigned short* Fp   = (unsigned short*)(w + o); o += (size_t)BB * LP * KP * 2;
    unsigned short* Kc   = (unsigned short*)(w + o); o += (size_t)BB * LP * KP * 2;
    unsigned short* Vc   = (unsigned short*)(w + o); o += (size_t)BB * N2 * LP * 2;  // must follow Kc (vdiff u32)
    unsigned short* U    = (unsigned short*)(w + o); o += (size_t)BB * LP * N2 * 2;

    detect_kernel<<<1, 64, 0, stream>>>((const unsigned int*)fg, flag, cnt);
    prep_kernel<<<BB * LP / 4, 256, 0, stream>>>(fg, bg, mask, flag, Fp, cnt, Kc, Vc);
    zpad_kernel<<<BB, 256, 0, stream>>>(cnt, Vc);

    flash_kernel<<<dim3(LP / 128, BB), 256, 0, stream>>>(Fp, Kc, Vc, cnt, U);

    gather_kernel<<<(BB * CC * HH * WW) / 256, 256, 0, stream>>>(U, out);
}

// Round 13
// 120.253 us; speedup vs baseline: 12.1077x; 1.0783x over previous
//
#include <hip/hip_runtime.h>
#include <hip/hip_bf16.h>
#include <hip/hip_fp16.h>

#define BB 8
#define CC 16
#define HH 128
#define WW 128
#define HD 64
#define WD 64
#define LP 4096
#define K1 144
#define KP 160
#define N2 256
#define E60 8.75651076269652e-27f   // exp(-60)

typedef __attribute__((ext_vector_type(8))) short bf16x8;
typedef __attribute__((ext_vector_type(8))) _Float16 f16x8;
typedef __attribute__((ext_vector_type(4))) float f32x4;

__device__ __forceinline__ unsigned short pack_rne(float x) {
    unsigned int u = __float_as_uint(x);
    return (unsigned short)((u + 0x7FFFu + ((u >> 16) & 1u)) >> 16);
}
__device__ __forceinline__ float bf2f(unsigned short u) {
    return __uint_as_float(((unsigned int)u) << 16);
}
__device__ __forceinline__ unsigned short f2h(float x) {
    return __half_as_ushort(__float2half(x));   // RNE
}
__device__ __forceinline__ float ld_in(const void* p, long idx, int bf) {
    if (bf) return bf2f(((const unsigned short*)p)[idx]);
    return ((const float*)p)[idx];
}
__device__ __forceinline__ void gl_lds16(const void* g, void* l) {
    __builtin_amdgcn_global_load_lds(
        (const __attribute__((address_space(1))) unsigned int*)g,
        (__attribute__((address_space(3))) unsigned int*)l,
        16, 0, 0);
}

// ---------------------------------------------------------------------------
// detect (lane-parallel) + zero the per-batch compaction counters.
// ---------------------------------------------------------------------------
__global__ void detect_kernel(const unsigned int* __restrict__ w,
                              int* __restrict__ flag, int* __restrict__ cnt) {
    int lane = threadIdx.x;
    if (lane < BB) cnt[lane] = 0;
    int c = 0;
    for (int i = lane; i < 256; i += 64) {
        unsigned int e = (w[i] >> 7) & 0xFF;
        if (e >= 100 && e <= 140) c++;
    }
#pragma unroll
    for (int s = 1; s < 64; s <<= 1) c += __shfl_xor(c, s);
    if (lane == 0) *flag = (c >= 192) ? 1 : 0;
}

// ---------------------------------------------------------------------------
// prep v6: block per (py, b); fg/bg even-grid rows staged into LDS with
// COALESCED loads (old version: stride-2 scalar gathers, ~2x line waste and
// the largest controllable kernel). Per-thread (px,g) computes a 4-channel
// slice of the 9-point stencil from LDS; Fp staged in LDS and written as one
// contiguous 20 KB uint4 block per row (64 consecutive patch rows). mm=1
// patches (~12/batch) compacted via LDS list + global atomicAdd slot, Kc
// from staged sBg, Vc direct global reads (rare path, r11-verified).
// ---------------------------------------------------------------------------
__global__ __launch_bounds__(256) void prep_kernel(
    const void* __restrict__ fg, const void* __restrict__ bg,
    const void* __restrict__ mask, const int* __restrict__ flagp,
    unsigned short* __restrict__ Fp, int* __restrict__ cnt,
    unsigned short* __restrict__ Kc, unsigned short* __restrict__ Vc)
{
    __shared__ float sFg[3][16][64];
    __shared__ float sBg[3][16][64];
    __shared__ float sMask[3][64];
    __shared__ __align__(16) unsigned short pFp[64][160];
    __shared__ float red[64][4];
    __shared__ float rn_sh[64];
    __shared__ int selPx[64];
    __shared__ int nsel;

    int bf = *flagp;
    int t = threadIdx.x;
    int py = blockIdx.x;
    int b  = blockIdx.y;

    if (t == 0) nsel = 0;

    // ---- stage even-grid rows Y = 2py-2, 2py, 2py+2 (zero if OOB)
#pragma unroll
    for (int i = 0; i < 12; i++) {
        int q = t + 256 * i;              // over [rr(3)][c(16)][xe(64)]
        int rr = q >> 10;
        int rem = q & 1023;
        int c = rem >> 6, xe = rem & 63;
        int Y = 2 * py + 2 * rr - 2;
        float fv = 0.f, bv = 0.f;
        if (Y >= 0 && Y < HH) {
            long gidx = ((long)(b * CC + c) * HH + Y) * WW + 2 * xe;
            fv = ld_in(fg, gidx, bf);
            bv = ld_in(bg, gidx, bf);
        }
        sFg[rr][c][xe] = fv;
        sBg[rr][c][xe] = bv;
    }
    if (t < 192) {
        int rr = t >> 6, xe = t & 63;
        int Y = 2 * py + 2 * rr - 2;
        float mv = 0.f;
        if (Y >= 0 && Y < HH)
            mv = ld_in(mask, ((long)b * HH + Y) * WW + 2 * xe, bf);
        sMask[rr][xe] = mv;
    }
    __syncthreads();

    // ---- per-thread (px, g): 4-channel slice of the 9-point stencil
    int px = t & 63, g = t >> 6;
    float ss = 0.f;
    for (int c = 4 * g; c < 4 * g + 4; c++) {
#pragma unroll
        for (int ky = 0; ky < 3; ky++)
#pragma unroll
            for (int kx = 0; kx < 3; kx++) {
                int xi = px + kx - 1;
                float fv = 0.f, bv = 0.f;
                if (xi >= 0 && xi < 64) { fv = sFg[ky][c][xi]; bv = sBg[ky][c][xi]; }
                ss += bv * bv;
                pFp[px][c * 9 + ky * 3 + kx] = f2h(fv);
            }
    }
    if (g == 0) {
#pragma unroll
        for (int e = K1; e < KP; e++) pFp[px][e] = 0;
    }
    red[px][g] = ss;
    __syncthreads();

    if (g == 0) {
        float S = red[px][0] + red[px][1] + red[px][2] + red[px][3];
        rn_sh[px] = 1.0f / fmaxf(sqrtf(S), 1e-4f);
    } else if (g == 1) {
        float mv = 0.f;
#pragma unroll
        for (int ky = 0; ky < 3; ky++)
#pragma unroll
            for (int kx = 0; kx < 3; kx++) {
                int xi = px + kx - 1;
                if (xi >= 0 && xi < 64) mv += sMask[ky][xi];
            }
        if (mv == 0.0f) selPx[atomicAdd(&nsel, 1)] = px;
    }
    __syncthreads();

    // ---- coalesced Fp write: 64 consecutive rows = one 20480 B block
    {
        const uint4* src = (const uint4*)&pFp[0][0];
        uint4* dst = (uint4*)(Fp + ((size_t)b * LP + (size_t)py * 64) * KP);
#pragma unroll
        for (int i = 0; i < 5; i++) dst[t + 256 * i] = src[t + 256 * i];
    }

    // ---- selected patches (rare): Kc/Vc, round-robin over waves
    int lane = t & 63;
    for (int i = g; i < nsel; i += 4) {
        int p2 = selPx[i];
        int j0 = 0;
        if (lane == 0) j0 = atomicAdd(&cnt[b], 1);
        int j = __shfl(j0, 0);
        float rn = rn_sh[p2];
        size_t kb = ((size_t)b * LP + j) * KP;
#pragma unroll
        for (int q = 0; q < 3; q++) {
            int e = lane + 64 * q;
            if (e < KP) {
                float bv = 0.f;
                if (e < K1) {
                    int c = e / 9;
                    int r9 = e - c * 9;
                    int ky = r9 / 3, kx = r9 - ky * 3;
                    int xi = p2 + kx - 1;
                    if (xi >= 0 && xi < 64) bv = sBg[ky][c][xi];  // OOB rows staged as 0
                }
                Kc[kb + e] = f2h(bv * rn);
            }
        }
        unsigned short* vcb = Vc + (size_t)b * N2 * LP + j;
#pragma unroll
        for (int q = 0; q < 4; q++) {
            int e = lane + 64 * q;
            int c = e >> 4, dy = (e >> 2) & 3, dx = e & 3;
            int Y = 2 * py + dy - 1, X = 2 * p2 + dx - 1;
            float v = 0.f;
            if (Y >= 0 && Y < HH && X >= 0 && X < WW)
                v = ld_in(bg, ((long)(b * CC + c) * HH + Y) * WW + X, bf);
            vcb[(size_t)e * LP] = pack_rne(v);
        }
    }
}

// ---------------------------------------------------------------------------
// zpad: zero Vc pad columns [n, roundup32(n)) -- mandatory (P=0 x poison-NaN
// would NaN the O-MFMA). Kc pad is provably harmless (z gated to 0 by j<n).
// ---------------------------------------------------------------------------
__global__ __launch_bounds__(256) void zpad_kernel(
    const int* __restrict__ cnt, unsigned short* __restrict__ Vc)
{
    int b = blockIdx.x;
    int n = cnt[b];
    int npad = (n + 31) & ~31;
    unsigned short* row = Vc + ((size_t)b * N2 + threadIdx.x) * LP;
    for (int j = n; j < npad; j++) row[j] = 0;
}

// ---------------------------------------------------------------------------
// flash v9 (sparse): r10 machinery (verified), U output bf16.
// nch = ceil(cnt/32) chunks (~1 for this data); mmh = (j < cnt); closed-form
// denom correction (4096 - 32*nch)*E60. Grid (32 p-tiles, 8 batches).
// ---------------------------------------------------------------------------
__global__ __launch_bounds__(256, 2) void flash_kernel(
    const unsigned short* __restrict__ Fp, const unsigned short* __restrict__ Kc,
    const unsigned short* __restrict__ Vc,  // [BB][256][4096] bf16 compacted
    const int* __restrict__ cnt,
    unsigned short* __restrict__ U)         // [BB][4096][256] bf16
{
    __shared__ char S_lds[2][26624];                // [K 10240 | V 16384]
    __shared__ unsigned short P_lds[4][2][16][40];  // per-wave, per-row-half

    int t = threadIdx.x;
    int wave = t >> 6, lane = t & 63;
    int l15 = lane & 15, lq = lane >> 4;

    int b = blockIdx.y;
    int pw = blockIdx.x * 128 + wave * 32;

    const unsigned short* Fp_b = Fp + (size_t)b * LP * KP;
    const unsigned short* Kc_b = Kc + (size_t)b * LP * KP;
    const unsigned short* Vc_b = Vc + (size_t)b * N2 * LP;

    int n = cnt[b];
    int nch = (n + 31) >> 5;

    // staging maps: 26 x 1KB calls, call i by wave i%4.
    unsigned int vdiff = (unsigned int)(Vc_b - Kc_b);
    unsigned int soff[7], smul[7];
#pragma unroll
    for (int j = 0; j < 7; j++) {
        int i = wave + 4 * j;
        int d = i * 1024 + lane * 16;
        if (i < 10) {
            int kc = d >> 11, slot = (d >> 9) & 3, row = (d >> 4) & 31;
            soff[j] = row * KP + kc * 32 + slot * 8;
            smul[j] = KP;
        } else {
            int d2 = d - 10240;
            int slot = d2 >> 12, c = (d2 >> 4) & 255;
            soff[j] = vdiff + c * LP + slot * 8;
            smul[j] = 1;
        }
    }
    int ncall = (wave < 2) ? 7 : 6;
    int dustart = wave * 1024;

    // F frags (f16): rows pw..pw+15 (A) and pw+16..pw+31 (B)
    f16x8 fA[5], fB[5];
    {
        size_t fbA = (size_t)(pw + l15) * KP + lq * 8;
        size_t fbB = (size_t)(pw + 16 + l15) * KP + lq * 8;
#pragma unroll
        for (int kc = 0; kc < 5; kc++) {
            fA[kc] = *(const f16x8*)&Fp_b[fbA + kc * 32];
            fB[kc] = *(const f16x8*)&Fp_b[fbB + kc * 32];
        }
    }

    f32x4 zero4 = {0.f, 0.f, 0.f, 0.f};
    f32x4 accA[16], accB[16];
#pragma unroll
    for (int nn = 0; nn < 16; nn++) { accA[nn] = zero4; accB[nn] = zero4; }
    float dA[4] = {0.f, 0.f, 0.f, 0.f};
    float dB[4] = {0.f, 0.f, 0.f, 0.f};

    if (nch > 0) {
#pragma unroll
        for (int j = 0; j < 7; j++)
            if (j < ncall)
                gl_lds16(Kc_b + soff[j], &S_lds[0][dustart + j * 4096]);
    }

    for (int ch = 0; ch < nch; ch++) {
        int cur = ch & 1;
        int l0 = ch * 32;
        __syncthreads();   // drains staging of buf[cur] + fences prev reads

        float mmh0 = (l0 + l15 < n) ? 1.f : 0.f;
        float mmh1 = (l0 + 16 + l15 < n) ? 1.f : 0.f;

        if (ch + 1 < nch) {
            size_t ln = (size_t)(l0 + 32);
#pragma unroll
            for (int j = 0; j < 7; j++)
                if (j < ncall)
                    gl_lds16(Kc_b + soff[j] + ln * smul[j], &S_lds[cur ^ 1][dustart + j * 4096]);
        }

        // ---- S phase: f16 single-pass; K frag reused by both row-halves
        float eA[2][4], eB[2][4];
#pragma unroll
        for (int h = 0; h < 2; h++) {
            const char* kb = &S_lds[cur][lq * 512 + (h * 16 + l15) * 16];
            f32x4 sA = zero4, sB = zero4;
#pragma unroll
            for (int kc = 0; kc < 5; kc++) {
                f16x8 kv = *(const f16x8*)(kb + kc * 2048);
                sA = __builtin_amdgcn_mfma_f32_16x16x32_f16(fA[kc], kv, sA, 0, 0, 0);
                sB = __builtin_amdgcn_mfma_f32_16x16x32_f16(fB[kc], kv, sB, 0, 0, 0);
            }
            float mmh = h ? mmh1 : mmh0;
#pragma unroll
            for (int r = 0; r < 4; r++) {
                float zA = (mmh > 0.f) ? 10.f * sA[r] : 0.f;
                float zB = (mmh > 0.f) ? 10.f * sB[r] : 0.f;
                float ea = __expf(zA - 60.f);
                float eb = __expf(zB - 60.f);
                dA[r] += ea; dB[r] += eb;
                eA[h][r] = ea * mmh; eB[h][r] = eb * mmh;
            }
        }

        // ---- P tiles (bf16): D-frag -> [p][l] per-wave LDS, read as A-frag
#pragma unroll
        for (int h = 0; h < 2; h++)
#pragma unroll
            for (int r = 0; r < 4; r++) {
                P_lds[wave][0][lq * 4 + r][h * 16 + l15] = pack_rne(eA[h][r]);
                P_lds[wave][1][lq * 4 + r][h * 16 + l15] = pack_rne(eB[h][r]);
            }
        bf16x8 pa0 = *(const bf16x8*)&P_lds[wave][0][l15][lq * 8];
        bf16x8 pa1 = *(const bf16x8*)&P_lds[wave][1][l15][lq * 8];

        // ---- O phase: 16 c-tiles; V frag reused by both row-halves
        const char* Vcp = &S_lds[cur][10240 + lq * 4096];
#pragma unroll
        for (int g = 0; g < 4; g++) {
            bf16x8 vb[4];
#pragma unroll
            for (int nn = 0; nn < 4; nn++)
                vb[nn] = *(const bf16x8*)(Vcp + (g * 64 + nn * 16 + l15) * 16);
#pragma unroll
            for (int nn = 0; nn < 4; nn++) {
                accA[g * 4 + nn] = __builtin_amdgcn_mfma_f32_16x16x32_bf16(pa0, vb[nn], accA[g * 4 + nn], 0, 0, 0);
                accB[g * 4 + nn] = __builtin_amdgcn_mfma_f32_16x16x32_bf16(pa1, vb[nn], accB[g * 4 + nn], 0, 0, 0);
            }
        }
    }

    // ---- epilogue: denom across the 16 lanes + closed-form mm=0 correction
#pragma unroll
    for (int s = 1; s < 16; s <<= 1)
#pragma unroll
        for (int r = 0; r < 4; r++) {
            dA[r] += __shfl_xor(dA[r], s);
            dB[r] += __shfl_xor(dB[r], s);
        }
    float corr = (float)(LP - nch * 32) * E60;
    float diA[4], diB[4];
#pragma unroll
    for (int r = 0; r < 4; r++) {
        diA[r] = 1.0f / (dA[r] + corr);
        diB[r] = 1.0f / (dB[r] + corr);
    }

    unsigned short* Uo = U + (size_t)b * LP * N2;
#pragma unroll
    for (int g = 0; g < 4; g++)
#pragma unroll
        for (int nn = 0; nn < 4; nn++) {
            int col = g * 64 + nn * 16 + l15;
#pragma unroll
            for (int r = 0; r < 4; r++) {
                Uo[(size_t)(pw + lq * 4 + r) * N2 + col] = pack_rne(accA[g * 4 + nn][r] * diA[r]);
                Uo[(size_t)(pw + 16 + lq * 4 + r) * N2 + col] = pack_rne(accB[g * 4 + nn][r] * diB[r]);
            }
        }
}

// ---------------------------------------------------------------------------
// gather / overlap-add (upright), bf16 U -> fp32 out
// ---------------------------------------------------------------------------
__global__ __launch_bounds__(256) void gather_kernel(
    const unsigned short* __restrict__ U, float* __restrict__ out)
{
    int idx = blockIdx.x * 256 + threadIdx.x;
    int ox = idx & 127;
    int t1 = idx >> 7;
    int oy = t1 & 127;
    int t2 = t1 >> 7;
    int c = t2 & 15;
    int b = t2 >> 4;

    float sum = 0.f;
    int d0y = (oy + 1) & 1, d0x = (ox + 1) & 1;
#pragma unroll
    for (int iy = 0; iy < 2; iy++) {
        int dy = d0y + 2 * iy;
        int y = (oy + 1 - dy) >> 1;
        if (y < 0 || y > 63) continue;
#pragma unroll
        for (int ix = 0; ix < 2; ix++) {
            int dx = d0x + 2 * ix;
            int x = (ox + 1 - dx) >> 1;
            if (x < 0 || x > 63) continue;
            sum += bf2f(U[((long)b * LP + y * 64 + x) * N2 + c * 16 + dy * 4 + dx]);
        }
    }
    out[idx] = sum * 0.25f;
}

// ---------------------------------------------------------------------------
extern "C" void kernel_launch(void* const* d_in, const int* in_sizes, int n_in,
                              void* d_out, int out_size, void* d_ws, size_t ws_size,
                              hipStream_t stream)
{
    const void* fg   = d_in[0];
    const void* bg   = d_in[1];
    const void* mask = d_in[2];
    float* out = (float*)d_out;

    char* w = (char*)d_ws;
    size_t o = 0;
    int*            flag = (int*)(w + o);            o += 16;
    int*            cnt  = (int*)(w + o);            o += 64;
    unsigned short* Fp   = (unsigned short*)(w + o); o += (size_t)BB * LP * KP * 2;
    unsigned short* Kc   = (unsigned short*)(w + o); o += (size_t)BB * LP * KP * 2;
    unsigned short* Vc   = (unsigned short*)(w + o); o += (size_t)BB * N2 * LP * 2;  // must follow Kc (vdiff u32)
    unsigned short* U    = (unsigned short*)(w + o); o += (size_t)BB * LP * N2 * 2;

    detect_kernel<<<1, 64, 0, stream>>>((const unsigned int*)fg, flag, cnt);
    prep_kernel<<<dim3(64, BB), 256, 0, stream>>>(fg, bg, mask, flag, Fp, cnt, Kc, Vc);
    zpad_kernel<<<BB, 256, 0, stream>>>(cnt, Vc);

    flash_kernel<<<dim3(LP / 128, BB), 256, 0, stream>>>(Fp, Kc, Vc, cnt, U);

    gather_kernel<<<(BB * CC * HH * WW) / 256, 256, 0, stream>>>(U, out);
}

// Round 14
// 117.526 us; speedup vs baseline: 12.3886x; 1.0232x over previous
//
#include <hip/hip_runtime.h>
#include <hip/hip_bf16.h>
#include <hip/hip_fp16.h>

#define BB 8
#define CC 16
#define HH 128
#define WW 128
#define HD 64
#define WD 64
#define LP 4096
#define K1 144
#define KP 160
#define N2 256
#define E60 8.75651076269652e-27f   // exp(-60)

typedef __attribute__((ext_vector_type(8))) short bf16x8;
typedef __attribute__((ext_vector_type(8))) _Float16 f16x8;
typedef __attribute__((ext_vector_type(4))) float f32x4;

__device__ __forceinline__ unsigned short pack_rne(float x) {
    unsigned int u = __float_as_uint(x);
    return (unsigned short)((u + 0x7FFFu + ((u >> 16) & 1u)) >> 16);
}
__device__ __forceinline__ float bf2f(unsigned short u) {
    return __uint_as_float(((unsigned int)u) << 16);
}
__device__ __forceinline__ unsigned short f2h(float x) {
    return __half_as_ushort(__float2half(x));   // RNE
}
__device__ __forceinline__ float ld_in(const void* p, long idx, int bf) {
    if (bf) return bf2f(((const unsigned short*)p)[idx]);
    return ((const float*)p)[idx];
}
__device__ __forceinline__ void gl_lds16(const void* g, void* l) {
    __builtin_amdgcn_global_load_lds(
        (const __attribute__((address_space(1))) unsigned int*)g,
        (__attribute__((address_space(3))) unsigned int*)l,
        16, 0, 0);
}

// ---------------------------------------------------------------------------
// prep v7: r13's verified prep v6, plus inline bf16-input detection (each
// block recomputes the flag from fg's first 256 dwords via
// __syncthreads_count -- L2-hot, frees the detect launch).
// Block per (py, b); fg/bg even-grid rows staged into LDS coalesced; 9-point
// stencil from LDS; Fp written as one contiguous 20 KB uint4 block per row.
// mm=1 patches (~12/batch) compacted via LDS list + global atomicAdd slot
// (cnt zeroed by a 64 B hipMemsetAsync before launch).
// ---------------------------------------------------------------------------
__global__ __launch_bounds__(256) void prep_kernel(
    const void* __restrict__ fg, const void* __restrict__ bg,
    const void* __restrict__ mask,
    unsigned short* __restrict__ Fp, int* __restrict__ cnt,
    unsigned short* __restrict__ Kc, unsigned short* __restrict__ Vc)
{
    __shared__ float sFg[3][16][64];
    __shared__ float sBg[3][16][64];
    __shared__ float sMask[3][64];
    __shared__ __align__(16) unsigned short pFp[64][160];
    __shared__ float red[64][4];
    __shared__ float rn_sh[64];
    __shared__ int selPx[64];
    __shared__ int nsel;

    int t = threadIdx.x;
    int py = blockIdx.x;
    int b  = blockIdx.y;

    if (t == 0) nsel = 0;

    // ---- inline dtype detect (replaces detect_kernel)
    unsigned int wv = ((const unsigned int*)fg)[t];
    unsigned int ex = (wv >> 7) & 0xFF;
    int bfcnt = __syncthreads_count(ex >= 100 && ex <= 140);
    int bf = (bfcnt >= 192);

    // ---- stage even-grid rows Y = 2py-2, 2py, 2py+2 (zero if OOB)
#pragma unroll
    for (int i = 0; i < 12; i++) {
        int q = t + 256 * i;              // over [rr(3)][c(16)][xe(64)]
        int rr = q >> 10;
        int rem = q & 1023;
        int c = rem >> 6, xe = rem & 63;
        int Y = 2 * py + 2 * rr - 2;
        float fv = 0.f, bv = 0.f;
        if (Y >= 0 && Y < HH) {
            long gidx = ((long)(b * CC + c) * HH + Y) * WW + 2 * xe;
            fv = ld_in(fg, gidx, bf);
            bv = ld_in(bg, gidx, bf);
        }
        sFg[rr][c][xe] = fv;
        sBg[rr][c][xe] = bv;
    }
    if (t < 192) {
        int rr = t >> 6, xe = t & 63;
        int Y = 2 * py + 2 * rr - 2;
        float mv = 0.f;
        if (Y >= 0 && Y < HH)
            mv = ld_in(mask, ((long)b * HH + Y) * WW + 2 * xe, bf);
        sMask[rr][xe] = mv;
    }
    __syncthreads();

    // ---- per-thread (px, g): 4-channel slice of the 9-point stencil
    int px = t & 63, g = t >> 6;
    float ss = 0.f;
    for (int c = 4 * g; c < 4 * g + 4; c++) {
#pragma unroll
        for (int ky = 0; ky < 3; ky++)
#pragma unroll
            for (int kx = 0; kx < 3; kx++) {
                int xi = px + kx - 1;
                float fv = 0.f, bv = 0.f;
                if (xi >= 0 && xi < 64) { fv = sFg[ky][c][xi]; bv = sBg[ky][c][xi]; }
                ss += bv * bv;
                pFp[px][c * 9 + ky * 3 + kx] = f2h(fv);
            }
    }
    if (g == 0) {
#pragma unroll
        for (int e = K1; e < KP; e++) pFp[px][e] = 0;
    }
    red[px][g] = ss;
    __syncthreads();

    if (g == 0) {
        float S = red[px][0] + red[px][1] + red[px][2] + red[px][3];
        rn_sh[px] = 1.0f / fmaxf(sqrtf(S), 1e-4f);
    } else if (g == 1) {
        float mv = 0.f;
#pragma unroll
        for (int ky = 0; ky < 3; ky++)
#pragma unroll
            for (int kx = 0; kx < 3; kx++) {
                int xi = px + kx - 1;
                if (xi >= 0 && xi < 64) mv += sMask[ky][xi];
            }
        if (mv == 0.0f) selPx[atomicAdd(&nsel, 1)] = px;
    }
    __syncthreads();

    // ---- coalesced Fp write: 64 consecutive rows = one 20480 B block
    {
        const uint4* src = (const uint4*)&pFp[0][0];
        uint4* dst = (uint4*)(Fp + ((size_t)b * LP + (size_t)py * 64) * KP);
#pragma unroll
        for (int i = 0; i < 5; i++) dst[t + 256 * i] = src[t + 256 * i];
    }

    // ---- selected patches (rare): Kc/Vc, round-robin over waves
    int lane = t & 63;
    for (int i = g; i < nsel; i += 4) {
        int p2 = selPx[i];
        int j0 = 0;
        if (lane == 0) j0 = atomicAdd(&cnt[b], 1);
        int j = __shfl(j0, 0);
        float rn = rn_sh[p2];
        size_t kb = ((size_t)b * LP + j) * KP;
#pragma unroll
        for (int q = 0; q < 3; q++) {
            int e = lane + 64 * q;
            if (e < KP) {
                float bv = 0.f;
                if (e < K1) {
                    int c = e / 9;
                    int r9 = e - c * 9;
                    int ky = r9 / 3, kx = r9 - ky * 3;
                    int xi = p2 + kx - 1;
                    if (xi >= 0 && xi < 64) bv = sBg[ky][c][xi];  // OOB rows staged as 0
                }
                Kc[kb + e] = f2h(bv * rn);
            }
        }
        unsigned short* vcb = Vc + (size_t)b * N2 * LP + j;
#pragma unroll
        for (int q = 0; q < 4; q++) {
            int e = lane + 64 * q;
            int c = e >> 4, dy = (e >> 2) & 3, dx = e & 3;
            int Y = 2 * py + dy - 1, X = 2 * p2 + dx - 1;
            float v = 0.f;
            if (Y >= 0 && Y < HH && X >= 0 && X < WW)
                v = ld_in(bg, ((long)(b * CC + c) * HH + Y) * WW + X, bf);
            vcb[(size_t)e * LP] = pack_rne(v);
        }
    }
}

// ---------------------------------------------------------------------------
// flash v10 (sparse): r13 machinery (verified), with zpad FOLDED IN -- after
// the last chunk's staging barrier, the V pad columns [n-32*ch, 32) are
// zeroed directly in LDS (global Vc pad may stay poisoned; the 0*NaN hazard
// is killed before any MFMA reads it). One extra uniform barrier on the last
// chunk only. nch = ceil(cnt/32); closed-form denom correction
// (4096 - 32*nch)*E60. Grid (32 p-tiles, 8 batches).
// ---------------------------------------------------------------------------
__global__ __launch_bounds__(256, 2) void flash_kernel(
    const unsigned short* __restrict__ Fp, const unsigned short* __restrict__ Kc,
    const unsigned short* __restrict__ Vc,  // [BB][256][4096] bf16 compacted
    const int* __restrict__ cnt,
    unsigned short* __restrict__ U)         // [BB][4096][256] bf16
{
    __shared__ char S_lds[2][26624];                // [K 10240 | V 16384]
    __shared__ unsigned short P_lds[4][2][16][40];  // per-wave, per-row-half

    int t = threadIdx.x;
    int wave = t >> 6, lane = t & 63;
    int l15 = lane & 15, lq = lane >> 4;

    int b = blockIdx.y;
    int pw = blockIdx.x * 128 + wave * 32;

    const unsigned short* Fp_b = Fp + (size_t)b * LP * KP;
    const unsigned short* Kc_b = Kc + (size_t)b * LP * KP;
    const unsigned short* Vc_b = Vc + (size_t)b * N2 * LP;

    int n = cnt[b];
    int nch = (n + 31) >> 5;

    // staging maps: 26 x 1KB calls, call i by wave i%4.
    unsigned int vdiff = (unsigned int)(Vc_b - Kc_b);
    unsigned int soff[7], smul[7];
#pragma unroll
    for (int j = 0; j < 7; j++) {
        int i = wave + 4 * j;
        int d = i * 1024 + lane * 16;
        if (i < 10) {
            int kc = d >> 11, slot = (d >> 9) & 3, row = (d >> 4) & 31;
            soff[j] = row * KP + kc * 32 + slot * 8;
            smul[j] = KP;
        } else {
            int d2 = d - 10240;
            int slot = d2 >> 12, c = (d2 >> 4) & 255;
            soff[j] = vdiff + c * LP + slot * 8;
            smul[j] = 1;
        }
    }
    int ncall = (wave < 2) ? 7 : 6;
    int dustart = wave * 1024;

    // F frags (f16): rows pw..pw+15 (A) and pw+16..pw+31 (B)
    f16x8 fA[5], fB[5];
    {
        size_t fbA = (size_t)(pw + l15) * KP + lq * 8;
        size_t fbB = (size_t)(pw + 16 + l15) * KP + lq * 8;
#pragma unroll
        for (int kc = 0; kc < 5; kc++) {
            fA[kc] = *(const f16x8*)&Fp_b[fbA + kc * 32];
            fB[kc] = *(const f16x8*)&Fp_b[fbB + kc * 32];
        }
    }

    f32x4 zero4 = {0.f, 0.f, 0.f, 0.f};
    f32x4 accA[16], accB[16];
#pragma unroll
    for (int nn = 0; nn < 16; nn++) { accA[nn] = zero4; accB[nn] = zero4; }
    float dA[4] = {0.f, 0.f, 0.f, 0.f};
    float dB[4] = {0.f, 0.f, 0.f, 0.f};

    if (nch > 0) {
#pragma unroll
        for (int j = 0; j < 7; j++)
            if (j < ncall)
                gl_lds16(Kc_b + soff[j], &S_lds[0][dustart + j * 4096]);
    }

    for (int ch = 0; ch < nch; ch++) {
        int cur = ch & 1;
        int l0 = ch * 32;
        __syncthreads();   // drains staging of buf[cur] + fences prev reads

        // ---- last chunk: zero V pad columns IN LDS (replaces zpad kernel)
        if (ch == nch - 1) {
            int nl = n - ch * 32;           // first invalid local column
            for (int jl = nl; jl < 32; jl++)
                *(unsigned short*)&S_lds[cur][10240 + ((jl >> 3) << 12) + t * 16 + ((jl & 7) << 1)] = 0;
            __syncthreads();
        }

        float mmh0 = (l0 + l15 < n) ? 1.f : 0.f;
        float mmh1 = (l0 + 16 + l15 < n) ? 1.f : 0.f;

        if (ch + 1 < nch) {
            size_t ln = (size_t)(l0 + 32);
#pragma unroll
            for (int j = 0; j < 7; j++)
                if (j < ncall)
                    gl_lds16(Kc_b + soff[j] + ln * smul[j], &S_lds[cur ^ 1][dustart + j * 4096]);
        }

        // ---- S phase: f16 single-pass; K frag reused by both row-halves
        float eA[2][4], eB[2][4];
#pragma unroll
        for (int h = 0; h < 2; h++) {
            const char* kb = &S_lds[cur][lq * 512 + (h * 16 + l15) * 16];
            f32x4 sA = zero4, sB = zero4;
#pragma unroll
            for (int kc = 0; kc < 5; kc++) {
                f16x8 kv = *(const f16x8*)(kb + kc * 2048);
                sA = __builtin_amdgcn_mfma_f32_16x16x32_f16(fA[kc], kv, sA, 0, 0, 0);
                sB = __builtin_amdgcn_mfma_f32_16x16x32_f16(fB[kc], kv, sB, 0, 0, 0);
            }
            float mmh = h ? mmh1 : mmh0;
#pragma unroll
            for (int r = 0; r < 4; r++) {
                float zA = (mmh > 0.f) ? 10.f * sA[r] : 0.f;
                float zB = (mmh > 0.f) ? 10.f * sB[r] : 0.f;
                float ea = __expf(zA - 60.f);
                float eb = __expf(zB - 60.f);
                dA[r] += ea; dB[r] += eb;
                eA[h][r] = ea * mmh; eB[h][r] = eb * mmh;
            }
        }

        // ---- P tiles (bf16): D-frag -> [p][l] per-wave LDS, read as A-frag
#pragma unroll
        for (int h = 0; h < 2; h++)
#pragma unroll
            for (int r = 0; r < 4; r++) {
                P_lds[wave][0][lq * 4 + r][h * 16 + l15] = pack_rne(eA[h][r]);
                P_lds[wave][1][lq * 4 + r][h * 16 + l15] = pack_rne(eB[h][r]);
            }
        bf16x8 pa0 = *(const bf16x8*)&P_lds[wave][0][l15][lq * 8];
        bf16x8 pa1 = *(const bf16x8*)&P_lds[wave][1][l15][lq * 8];

        // ---- O phase: 16 c-tiles; V frag reused by both row-halves
        const char* Vcp = &S_lds[cur][10240 + lq * 4096];
#pragma unroll
        for (int g = 0; g < 4; g++) {
            bf16x8 vb[4];
#pragma unroll
            for (int nn = 0; nn < 4; nn++)
                vb[nn] = *(const bf16x8*)(Vcp + (g * 64 + nn * 16 + l15) * 16);
#pragma unroll
            for (int nn = 0; nn < 4; nn++) {
                accA[g * 4 + nn] = __builtin_amdgcn_mfma_f32_16x16x32_bf16(pa0, vb[nn], accA[g * 4 + nn], 0, 0, 0);
                accB[g * 4 + nn] = __builtin_amdgcn_mfma_f32_16x16x32_bf16(pa1, vb[nn], accB[g * 4 + nn], 0, 0, 0);
            }
        }
    }

    // ---- epilogue: denom across the 16 lanes + closed-form mm=0 correction
#pragma unroll
    for (int s = 1; s < 16; s <<= 1)
#pragma unroll
        for (int r = 0; r < 4; r++) {
            dA[r] += __shfl_xor(dA[r], s);
            dB[r] += __shfl_xor(dB[r], s);
        }
    float corr = (float)(LP - nch * 32) * E60;
    float diA[4], diB[4];
#pragma unroll
    for (int r = 0; r < 4; r++) {
        diA[r] = 1.0f / (dA[r] + corr);
        diB[r] = 1.0f / (dB[r] + corr);
    }

    unsigned short* Uo = U + (size_t)b * LP * N2;
#pragma unroll
    for (int g = 0; g < 4; g++)
#pragma unroll
        for (int nn = 0; nn < 4; nn++) {
            int col = g * 64 + nn * 16 + l15;
#pragma unroll
            for (int r = 0; r < 4; r++) {
                Uo[(size_t)(pw + lq * 4 + r) * N2 + col] = pack_rne(accA[g * 4 + nn][r] * diA[r]);
                Uo[(size_t)(pw + 16 + lq * 4 + r) * N2 + col] = pack_rne(accB[g * 4 + nn][r] * diB[r]);
            }
        }
}

// ---------------------------------------------------------------------------
// gather / overlap-add (upright), bf16 U -> fp32 out
// ---------------------------------------------------------------------------
__global__ __launch_bounds__(256) void gather_kernel(
    const unsigned short* __restrict__ U, float* __restrict__ out)
{
    int idx = blockIdx.x * 256 + threadIdx.x;
    int ox = idx & 127;
    int t1 = idx >> 7;
    int oy = t1 & 127;
    int t2 = t1 >> 7;
    int c = t2 & 15;
    int b = t2 >> 4;

    float sum = 0.f;
    int d0y = (oy + 1) & 1, d0x = (ox + 1) & 1;
#pragma unroll
    for (int iy = 0; iy < 2; iy++) {
        int dy = d0y + 2 * iy;
        int y = (oy + 1 - dy) >> 1;
        if (y < 0 || y > 63) continue;
#pragma unroll
        for (int ix = 0; ix < 2; ix++) {
            int dx = d0x + 2 * ix;
            int x = (ox + 1 - dx) >> 1;
            if (x < 0 || x > 63) continue;
            sum += bf2f(U[((long)b * LP + y * 64 + x) * N2 + c * 16 + dy * 4 + dx]);
        }
    }
    out[idx] = sum * 0.25f;
}

// ---------------------------------------------------------------------------
extern "C" void kernel_launch(void* const* d_in, const int* in_sizes, int n_in,
                              void* d_out, int out_size, void* d_ws, size_t ws_size,
                              hipStream_t stream)
{
    const void* fg   = d_in[0];
    const void* bg   = d_in[1];
    const void* mask = d_in[2];
    float* out = (float*)d_out;

    char* w = (char*)d_ws;
    size_t o = 0;
    int*            cnt  = (int*)(w + o);            o += 64;
    unsigned short* Fp   = (unsigned short*)(w + o); o += (size_t)BB * LP * KP * 2;
    unsigned short* Kc   = (unsigned short*)(w + o); o += (size_t)BB * LP * KP * 2;
    unsigned short* Vc   = (unsigned short*)(w + o); o += (size_t)BB * N2 * LP * 2;  // must follow Kc (vdiff u32)
    unsigned short* U    = (unsigned short*)(w + o); o += (size_t)BB * LP * N2 * 2;

    hipMemsetAsync(cnt, 0, 64, stream);
    prep_kernel<<<dim3(64, BB), 256, 0, stream>>>(fg, bg, mask, Fp, cnt, Kc, Vc);
    flash_kernel<<<dim3(LP / 128, BB), 256, 0, stream>>>(Fp, Kc, Vc, cnt, U);
    gather_kernel<<<(BB * CC * HH * WW) / 256, 256, 0, stream>>>(U, out);
}